// Round 12
// baseline (8859.256 us; speedup 1.0000x reference)
//
#include <hip/hip_runtime.h>
#include <math.h>

// ---------------- constants ----------------
#define NIMG 32
#define NP2  196        // patches per image
#define PTOK 197        // tokens per image
#define DIM  768
#define NH   12
#define VD   64
#define MLPD 3072
#define ROWS (NIMG*PTOK)   // 6304
#define PROWS (NIMG*NP2)   // 6272
#define MPAD 6400          // padded rows for activation planes (glds over-read)
#define PSTR 208           // padded token stride for q/k/v planes
#define BHN (NIMG*NH)      // 384

typedef float f32x4 __attribute__((ext_vector_type(4)));
typedef short bf16x8 __attribute__((ext_vector_type(8)));
typedef unsigned short u16x8 __attribute__((ext_vector_type(8)));
typedef unsigned short u16x4 __attribute__((ext_vector_type(4)));

__device__ __forceinline__ unsigned short f2bf(float x) {
    unsigned int u = __float_as_uint(x);
    return (unsigned short)((u + 0x7FFFu + ((u >> 16) & 1u)) >> 16);
}
__device__ __forceinline__ float bfhi(unsigned short h) {
    return __uint_as_float(((unsigned int)h) << 16);
}
// async global->LDS, 16B per lane; LDS dest = wave base + lane*16 (linear)
__device__ __forceinline__ void glds16(const unsigned short* g, unsigned short* l) {
    __builtin_amdgcn_global_load_lds(
        (const __attribute__((address_space(1))) unsigned int*)g,
        (__attribute__((address_space(3))) unsigned int*)l, 16, 0, 0);
}

// ---------------- patchify -> hi/lo bf16 planes ----------------
__global__ __launch_bounds__(256) void patchify_kernel(const float* __restrict__ img,
                                                       unsigned short* __restrict__ ph,
                                                       unsigned short* __restrict__ pl)
{
    int idx = blockIdx.x * 256 + threadIdx.x;
    if (idx >= PROWS * DIM) return;
    int row = idx / DIM, kk = idx % DIM;
    int b = row / NP2, p = row % NP2;
    int i = p / 14, j = p % 14;
    int c = kk >> 8, r = kk & 255;
    int pr = r >> 4, pw = r & 15;
    float v = img[(((size_t)b*3 + c)*224 + i*16 + pr)*224 + j*16 + pw];
    unsigned short hi = f2bf(v);
    ph[idx] = hi;
    pl[idx] = f2bf(v - bfhi(hi));
}

// ---------------- class token + pos row0 ----------------
__global__ __launch_bounds__(256) void class_pos_kernel(const float* __restrict__ ct,
                                                        const float* __restrict__ pos,
                                                        float* __restrict__ x)
{
    int idx = blockIdx.x * 256 + threadIdx.x;
    if (idx >= NIMG * DIM) return;
    int b = idx / DIM, d = idx % DIM;
    x[(size_t)b * PTOK * DIM + d] = ct[d] + pos[d];
}

// ---------------- weight conversion: W[K][N] fp32 -> blocked hi/lo bf16 ----------------
// Blocked: [N/128][K/32][128][32] row-major (n_in, k_in), 4096 elems / 8KB per block.
__device__ __forceinline__ void conv_body(const float* __restrict__ W,
    unsigned short* __restrict__ Bh, unsigned short* __restrict__ Bl, int K, int N)
{
    int idx = blockIdx.x * 256 + threadIdx.x;
    if (idx >= N * (K >> 5)) return;
    int kb = idx / N;
    int n  = idx - kb * N;
    size_t off = (((size_t)(n >> 7) * (K >> 5) + kb) * 128 + (n & 127)) * 32;
    #pragma unroll
    for (int u = 0; u < 4; ++u) {
        u16x8 h, l;
        #pragma unroll
        for (int j = 0; j < 8; ++j) {
            float x = W[(size_t)(kb * 32 + u * 8 + j) * N + n];
            unsigned short hh = f2bf(x);
            h[j] = hh;
            l[j] = f2bf(x - bfhi(hh));
        }
        *(u16x8*)&Bh[off + u * 8] = h;
        *(u16x8*)&Bl[off + u * 8] = l;
    }
}

__global__ __launch_bounds__(256) void convert_one(const float* __restrict__ W,
    unsigned short* __restrict__ Bh, unsigned short* __restrict__ Bl, int K, int N)
{
    conv_body(W, Bh, Bl, K, N);
}

__global__ __launch_bounds__(256) void convert_layer(
    const float* __restrict__ qw, const float* __restrict__ mw,
    const float* __restrict__ w1, const float* __restrict__ w2,
    unsigned short* qh, unsigned short* ql, unsigned short* mh, unsigned short* ml,
    unsigned short* h1, unsigned short* l1, unsigned short* h2, unsigned short* l2)
{
    switch (blockIdx.y) {
        case 0: conv_body(qw, qh, ql, DIM, 3*NH*VD); break;
        case 1: conv_body(mw, mh, ml, DIM, DIM);     break;
        case 2: conv_body(w1, h1, l1, DIM, MLPD);    break;
        case 3: conv_body(w2, h2, l2, MLPD, DIM);    break;
    }
}

// ---------------- shared epilogue ----------------
template<int MODE>
__device__ __forceinline__ void epi_store(
    int r, int c, float val, float* __restrict__ C, int M, int N,
    const float* __restrict__ bias, const float* __restrict__ res,
    const float* __restrict__ pos,
    unsigned int* __restrict__ qo, unsigned int* __restrict__ ko, unsigned int* __restrict__ vo,
    unsigned short* __restrict__ oph, unsigned short* __restrict__ opl)
{
    if (MODE == 1) {
        int b = r / NP2, p = r - b * NP2;
        C[((size_t)b * PTOK + 1 + p) * DIM + c] = val + pos[(size_t)(p + 1) * DIM + c];
    } else if (MODE == 2) {
        int b = r / PTOK, p = r - b * PTOK;
        int t = c % 3, hv = c / 3;
        int hd = hv >> 6, vv = hv & 63;
        size_t bh = (size_t)b * NH + hd;
        float sv = (t == 0) ? val * 0.125f : val;
        unsigned short hi = f2bf(sv);
        unsigned short lo = f2bf(sv - bfhi(hi));
        unsigned int w32 = (unsigned int)hi | ((unsigned int)lo << 16);
        if (t == 2) vo[(bh * 64 + vv) * PSTR + p] = w32;
        else if (t == 0) qo[(bh * PSTR + p) * 64 + vv] = w32;
        else ko[(bh * PSTR + p) * 64 + vv] = w32;
    } else if (MODE == 3) {
        float tmp = val + bias[c];
        float gel = 0.5f * tmp * (1.0f + erff(tmp * 0.70710678118654752f));
        unsigned short hi = f2bf(gel);
        oph[(size_t)r * N + c] = hi;
        opl[(size_t)r * N + c] = f2bf(gel - bfhi(hi));
    } else if (MODE == 4) {
        C[(size_t)r * N + c] = res[(size_t)r * N + c] + val;
    } else if (MODE == 5) {
        C[(size_t)r * N + c] = res[(size_t)r * N + c] + val + bias[c];
    }
}

// ---------------- mgemm: 128x128 tile, A direct-from-L2, B in LDS (16KB), 3 blocks/CU ----------------
// r11 cycle model: old structure was LDS-throughput-bound (384KB/step/CU ~3000cyc vs
// MFMA 932). A-fragments are per-wave 16B/lane reads -> load straight from global
// (A is XCD-local, L2-resident per r6/r9 FETCH data). LDS now carries ONLY B:
// 144KB/step/CU (~1125cyc); A rides the parallel L2/TA pipe (~710cyc); MFMA 700cyc.
// Register budget: acc 64 AGPR + bfrag 32 + afrag 8 + addr ~= 140 -> (256,3) cap ~170.
// (256,4)=128 cap WOULD SPILL (r5/r10 signature: VGPR~64, WRITE_SIZE~GBs). 
// Per-acc MFMA order hh->hl->lh unchanged => bit-identical to r9.
template<int MODE>
__global__ __launch_bounds__(256, 3) void mgemm(
    const unsigned short* __restrict__ Ah, const unsigned short* __restrict__ Al,
    const unsigned short* __restrict__ Bh, const unsigned short* __restrict__ Bl,
    float* __restrict__ C, int M, int N, int K, int gm, int gn,
    const float* __restrict__ bias, const float* __restrict__ res,
    const float* __restrict__ pos,
    unsigned int* __restrict__ qo, unsigned int* __restrict__ ko, unsigned int* __restrict__ vo,
    unsigned short* __restrict__ oph, unsigned short* __restrict__ opl)
{
    __shared__ unsigned short SBh[4096];
    __shared__ unsigned short SBl[4096];

    const int tid = threadIdx.x;
    // bijective XCD chunk remap (r9 mapping; r11 supertile reverted — it raised FETCH)
    const int nwg = gm * gn;
    const int q = nwg >> 3, r = nwg & 7;
    const int xcd = blockIdx.x & 7, li = blockIdx.x >> 3;
    const int seq = xcd * q + (xcd < r ? xcd : r) + li;
    const int mt = seq / gn, nt = seq - mt * gn;
    const int m0 = mt * 128, n0 = nt * 128;

    const int wave = tid >> 6, lane = tid & 63;
    const int wm = (wave >> 1) * 64, wn = (wave & 1) * 64;
    const int lr = lane & 15, lg = lane >> 4;

    // B staging source coords (slot pre-swizzled; linear LDS holds swizzled tile)
    const int r0 = tid >> 2, sl = tid & 3;
    const int s0s = sl ^ ((r0 >> 1) & 3);
    const size_t boff0 = (size_t)(n0 >> 7) * (K >> 5) * 4096 + (size_t)r0 * 32 + s0s * 8;

    // B frag read offsets (loop-invariant, swizzled)
    int bro[4];
    #pragma unroll
    for (int i = 0; i < 4; ++i) {
        int rowB = wn + i * 16 + lr;
        bro[i] = rowB * 32 + ((lg ^ ((rowB >> 1) & 3)) * 8);
    }

    // A fragment base pointers (global, per-lane): row = m0+wm+mi*16+lr, k = ks*32+lg*8
    const unsigned short* pAh = Ah + (size_t)(m0 + wm + lr) * K + lg * 8;
    const unsigned short* pAl = Al + (size_t)(m0 + wm + lr) * K + lg * 8;

    f32x4 acc[4][4];
    #pragma unroll
    for (int i = 0; i < 4; ++i)
        #pragma unroll
        for (int j = 0; j < 4; ++j)
            #pragma unroll
            for (int e = 0; e < 4; ++e) acc[i][j][e] = 0.f;

    const int kSteps = K >> 5;
    #pragma unroll 1
    for (int ks = 0; ks < kSteps; ++ks) {
        __syncthreads();                 // prev B frag reads done
        const size_t bk = (size_t)ks * 4096;
        glds16(Bh + boff0 + bk, SBh + tid * 8);
        glds16(Bh + boff0 + bk + 2048, SBh + 2048 + tid * 8);
        glds16(Bl + boff0 + bk, SBl + tid * 8);
        glds16(Bl + boff0 + bk + 2048, SBl + 2048 + tid * 8);
        __syncthreads();                 // drains vmcnt before barrier

        bf16x8 bfh[4], bfl[4];
        #pragma unroll
        for (int ni = 0; ni < 4; ++ni) {
            bfh[ni] = *(const bf16x8*)&SBh[bro[ni]];
            bfl[ni] = *(const bf16x8*)&SBl[bro[ni]];
        }
        const size_t ak = (size_t)ks * 32;
        #pragma unroll
        for (int mi = 0; mi < 4; ++mi) {
            bf16x8 afh = *(const bf16x8*)(pAh + (size_t)mi * 16 * K + ak);
            bf16x8 afl = *(const bf16x8*)(pAl + (size_t)mi * 16 * K + ak);
            #pragma unroll
            for (int ni = 0; ni < 4; ++ni)
                acc[mi][ni] = __builtin_amdgcn_mfma_f32_16x16x32_bf16(afh, bfh[ni], acc[mi][ni], 0, 0, 0);
            #pragma unroll
            for (int ni = 0; ni < 4; ++ni)
                acc[mi][ni] = __builtin_amdgcn_mfma_f32_16x16x32_bf16(afh, bfl[ni], acc[mi][ni], 0, 0, 0);
            #pragma unroll
            for (int ni = 0; ni < 4; ++ni)
                acc[mi][ni] = __builtin_amdgcn_mfma_f32_16x16x32_bf16(afl, bfh[ni], acc[mi][ni], 0, 0, 0);
        }
    }

    #pragma unroll
    for (int mi = 0; mi < 4; ++mi) {
        #pragma unroll
        for (int ni = 0; ni < 4; ++ni) {
            f32x4 v = acc[mi][ni];
            int c = n0 + wn + ni * 16 + lr;
            #pragma unroll
            for (int rr = 0; rr < 4; ++rr) {
                int rr2 = m0 + wm + mi * 16 + lg * 4 + rr;
                if (rr2 >= M) continue;
                epi_store<MODE>(rr2, c, v[rr], C, M, N, bias, res, pos, qo, ko, vo, oph, opl);
            }
        }
    }
}

// ---------------- LayerNorm -> hi/lo bf16 planes ----------------
__global__ __launch_bounds__(256) void ln_kernel(const float* __restrict__ x,
                                                 const float* __restrict__ w,
                                                 const float* __restrict__ b,
                                                 unsigned short* __restrict__ oh,
                                                 unsigned short* __restrict__ ol, int rows)
{
    int wave = threadIdx.x >> 6, lane = threadIdx.x & 63;
    int row = blockIdx.x * 4 + wave;
    if (row >= rows) return;
    const float* xr = x + (size_t)row * DIM;
    float vals[12];
    float sum = 0.f;
    #pragma unroll
    for (int u = 0; u < 12; ++u) { vals[u] = xr[u * 64 + lane]; sum += vals[u]; }
    #pragma unroll
    for (int off = 32; off; off >>= 1) sum += __shfl_xor(sum, off);
    float mean = sum * (1.f / DIM);
    float vs = 0.f;
    #pragma unroll
    for (int u = 0; u < 12; ++u) { float d = vals[u] - mean; vs += d * d; }
    #pragma unroll
    for (int off = 32; off; off >>= 1) vs += __shfl_xor(vs, off);
    float rstd = rsqrtf(vs * (1.f / DIM) + 1e-5f);
    #pragma unroll
    for (int u = 0; u < 12; ++u) {
        int d = u * 64 + lane;
        float v = (vals[u] - mean) * rstd * w[d] + b[d];
        unsigned short hi = f2bf(v);
        oh[(size_t)row * DIM + d] = hi;
        ol[(size_t)row * DIM + d] = f2bf(v - bfhi(hi));
    }
}

// ---------------- MFMA attention (epilogue -> hi/lo planes) ----------------
__global__ __launch_bounds__(256) void attn_mfma(
    const unsigned int* __restrict__ qp, const unsigned int* __restrict__ kp,
    const unsigned int* __restrict__ vtp,
    unsigned short* __restrict__ oh, unsigned short* __restrict__ ol)
{
    __shared__ unsigned short KVh[64 * 72];
    __shared__ unsigned short KVl[64 * 72];
    __shared__ unsigned short Ph[64 * 72];
    __shared__ unsigned short Pl[64 * 72];

    const int tid = threadIdx.x;
    const int w = tid >> 6, lane = tid & 63;
    const int l = lane & 15, g = lane >> 4;
    const int bh = blockIdx.y, q0 = blockIdx.x * 64;
    const int b = bh / NH, hd = bh - b * NH;

    int qrow = q0 + 16 * w + l;
    if (qrow >= PTOK) qrow = 0;
    const unsigned int* qbase = qp + ((size_t)bh * PSTR + qrow) * 64;
    bf16x8 qAh[2], qAl[2];
    #pragma unroll
    for (int ks = 0; ks < 2; ++ks) {
        const unsigned int* p = qbase + 32 * ks + 8 * g;
        uint4 a = *(const uint4*)p;
        uint4 c = *(const uint4*)(p + 4);
        bf16x8 h8, l8;
        h8[0]=(short)a.x; h8[1]=(short)a.y; h8[2]=(short)a.z; h8[3]=(short)a.w;
        h8[4]=(short)c.x; h8[5]=(short)c.y; h8[6]=(short)c.z; h8[7]=(short)c.w;
        l8[0]=(short)(a.x>>16); l8[1]=(short)(a.y>>16); l8[2]=(short)(a.z>>16); l8[3]=(short)(a.w>>16);
        l8[4]=(short)(c.x>>16); l8[5]=(short)(c.y>>16); l8[6]=(short)(c.z>>16); l8[7]=(short)(c.w>>16);
        qAh[ks] = h8; qAl[ks] = l8;
    }

    f32x4 s[13];
    #pragma unroll
    for (int t = 0; t < 13; ++t)
        #pragma unroll
        for (int e = 0; e < 4; ++e) s[t][e] = 0.f;

    for (int c = 0; c < 4; ++c) {
        __syncthreads();
        const int rows = (c < 3) ? 64 : 16;
        for (int u = tid; u < rows * 16; u += 256) {
            int r = u >> 4, cc = u & 15;
            int j = c * 64 + r;
            uint4 wv = make_uint4(0, 0, 0, 0);
            if (j < PTOK) wv = *(const uint4*)(kp + ((size_t)bh * PSTR + j) * 64 + cc * 4);
            u16x4 h4, l4;
            h4[0]=(unsigned short)wv.x; h4[1]=(unsigned short)wv.y;
            h4[2]=(unsigned short)wv.z; h4[3]=(unsigned short)wv.w;
            l4[0]=(unsigned short)(wv.x>>16); l4[1]=(unsigned short)(wv.y>>16);
            l4[2]=(unsigned short)(wv.z>>16); l4[3]=(unsigned short)(wv.w>>16);
            *(u16x4*)&KVh[r * 72 + cc * 4] = h4;
            *(u16x4*)&KVl[r * 72 + cc * 4] = l4;
        }
        __syncthreads();
        const int tc = (c < 3) ? 4 : 1;
        for (int t = 0; t < tc; ++t) {
            int ti = c * 4 + t;
            #pragma unroll
            for (int ks = 0; ks < 2; ++ks) {
                bf16x8 kh = *(const bf16x8*)&KVh[(16 * t + l) * 72 + 32 * ks + 8 * g];
                bf16x8 kl = *(const bf16x8*)&KVl[(16 * t + l) * 72 + 32 * ks + 8 * g];
                s[ti] = __builtin_amdgcn_mfma_f32_16x16x32_bf16(qAh[ks], kh, s[ti], 0, 0, 0);
                s[ti] = __builtin_amdgcn_mfma_f32_16x16x32_bf16(qAh[ks], kl, s[ti], 0, 0, 0);
                s[ti] = __builtin_amdgcn_mfma_f32_16x16x32_bf16(qAl[ks], kh, s[ti], 0, 0, 0);
            }
        }
    }

    if (l >= 5) {
        #pragma unroll
        for (int e = 0; e < 4; ++e) s[12][e] = -1e30f;
    }

    float mx[4], rs[4];
    #pragma unroll
    for (int e = 0; e < 4; ++e) {
        float m = s[0][e];
        #pragma unroll
        for (int t = 1; t < 13; ++t) m = fmaxf(m, s[t][e]);
        #pragma unroll
        for (int off = 1; off < 16; off <<= 1) m = fmaxf(m, __shfl_xor(m, off));
        mx[e] = m;
    }
    #pragma unroll
    for (int e = 0; e < 4; ++e) {
        float sum = 0.f;
        #pragma unroll
        for (int t = 0; t < 13; ++t) {
            float p = __expf(s[t][e] - mx[e]);
            s[t][e] = p;
            sum += p;
        }
        #pragma unroll
        for (int off = 1; off < 16; off <<= 1) sum += __shfl_xor(sum, off);
        rs[e] = 1.f / sum;
    }

    f32x4 o[4];
    #pragma unroll
    for (int t = 0; t < 4; ++t)
        #pragma unroll
        for (int e = 0; e < 4; ++e) o[t][e] = 0.f;

    for (int c = 0; c < 4; ++c) {
        __syncthreads();
        const int cols = (c < 3) ? 64 : 32;
        const int cpr = cols >> 2;
        for (int u = tid; u < 64 * cpr; u += 256) {
            int r = u / cpr, cc = u % cpr;
            int jbase = c * 64 + cc * 4;
            uint4 wv;
            if (c < 3) {
                wv = *(const uint4*)(vtp + ((size_t)bh * 64 + r) * PSTR + jbase);
            } else {
                unsigned int t0 = (jbase + 0 < PTOK) ? vtp[((size_t)bh * 64 + r) * PSTR + jbase + 0] : 0u;
                unsigned int t1 = (jbase + 1 < PTOK) ? vtp[((size_t)bh * 64 + r) * PSTR + jbase + 1] : 0u;
                unsigned int t2 = (jbase + 2 < PTOK) ? vtp[((size_t)bh * 64 + r) * PSTR + jbase + 2] : 0u;
                unsigned int t3 = (jbase + 3 < PTOK) ? vtp[((size_t)bh * 64 + r) * PSTR + jbase + 3] : 0u;
                wv = make_uint4(t0, t1, t2, t3);
            }
            u16x4 h4, l4;
            h4[0]=(unsigned short)wv.x; h4[1]=(unsigned short)wv.y;
            h4[2]=(unsigned short)wv.z; h4[3]=(unsigned short)wv.w;
            l4[0]=(unsigned short)(wv.x>>16); l4[1]=(unsigned short)(wv.y>>16);
            l4[2]=(unsigned short)(wv.z>>16); l4[3]=(unsigned short)(wv.w>>16);
            *(u16x4*)&KVh[r * 72 + cc * 4] = h4;
            *(u16x4*)&KVl[r * 72 + cc * 4] = l4;
        }
        const int tc = (c < 3) ? 4 : 1;
        for (int t = 0; t < tc; ++t) {
            int ti = c * 4 + t;
            #pragma unroll
            for (int e = 0; e < 4; ++e) {
                int row = 16 * w + 4 * g + e, col = 16 * t + l;
                float pv = s[ti][e];
                unsigned short hi = f2bf(pv);
                Ph[row * 72 + col] = hi;
                Pl[row * 72 + col] = f2bf(pv - bfhi(hi));
            }
        }
        __syncthreads();
        const int ksn = (c < 3) ? 2 : 1;
        for (int ks = 0; ks < ksn; ++ks) {
            bf16x8 pa_h = *(const bf16x8*)&Ph[(16 * w + l) * 72 + 32 * ks + 8 * g];
            bf16x8 pa_l = *(const bf16x8*)&Pl[(16 * w + l) * 72 + 32 * ks + 8 * g];
            #pragma unroll
            for (int tv = 0; tv < 4; ++tv) {
                bf16x8 vh = *(const bf16x8*)&KVh[(16 * tv + l) * 72 + 32 * ks + 8 * g];
                bf16x8 vl = *(const bf16x8*)&KVl[(16 * tv + l) * 72 + 32 * ks + 8 * g];
                o[tv] = __builtin_amdgcn_mfma_f32_16x16x32_bf16(pa_h, vh, o[tv], 0, 0, 0);
                o[tv] = __builtin_amdgcn_mfma_f32_16x16x32_bf16(pa_h, vl, o[tv], 0, 0, 0);
                o[tv] = __builtin_amdgcn_mfma_f32_16x16x32_bf16(pa_l, vh, o[tv], 0, 0, 0);
            }
        }
    }

    #pragma unroll
    for (int tv = 0; tv < 4; ++tv) {
        #pragma unroll
        for (int e = 0; e < 4; ++e) {
            int q = q0 + 16 * w + 4 * g + e;
            if (q < PTOK) {
                float v = o[tv][e] * rs[e];
                size_t idx = ((size_t)(b * PTOK + q)) * DIM + hd * 64 + 16 * tv + l;
                unsigned short hi = f2bf(v);
                oh[idx] = hi;
                ol[idx] = f2bf(v - bfhi(hi));
            }
        }
    }
}

// ---------------- head: logits + softmax ----------------
__global__ __launch_bounds__(256) void head_kernel(const float* __restrict__ x,
                                                   const float* __restrict__ W,
                                                   const float* __restrict__ bias,
                                                   float* __restrict__ out)
{
    __shared__ __align__(16) float xl[DIM];
    __shared__ float red[4];
    int b = blockIdx.x;
    const float* xr = x + (size_t)b * PTOK * DIM;
    for (int idx = threadIdx.x; idx < DIM; idx += 256) xl[idx] = xr[idx];
    __syncthreads();

    float logit[4];
    #pragma unroll
    for (int u = 0; u < 4; ++u) {
        int c = threadIdx.x + u * 256;
        float acc = (c < 1000) ? bias[c] : -INFINITY;
        if (c < 1000) {
            for (int k = 0; k < DIM; k += 4) {
                float4 xv = *(const float4*)&xl[k];
                acc += xv.x * W[(size_t)k * 1000 + c]
                     + xv.y * W[(size_t)(k + 1) * 1000 + c]
                     + xv.z * W[(size_t)(k + 2) * 1000 + c]
                     + xv.w * W[(size_t)(k + 3) * 1000 + c];
            }
        }
        logit[u] = acc;
    }
    int lane = threadIdx.x & 63, wv = threadIdx.x >> 6;
    float m = fmaxf(fmaxf(logit[0], logit[1]), fmaxf(logit[2], logit[3]));
    #pragma unroll
    for (int off = 32; off; off >>= 1) m = fmaxf(m, __shfl_xor(m, off));
    if (lane == 0) red[wv] = m;
    __syncthreads();
    m = fmaxf(fmaxf(red[0], red[1]), fmaxf(red[2], red[3]));

    float p[4]; float sum = 0.f;
    #pragma unroll
    for (int u = 0; u < 4; ++u) {
        int c = threadIdx.x + u * 256;
        p[u] = (c < 1000) ? expf(logit[u] - m) : 0.f;
        sum += p[u];
    }
    #pragma unroll
    for (int off = 32; off; off >>= 1) sum += __shfl_xor(sum, off);
    __syncthreads();
    if (lane == 0) red[wv] = sum;
    __syncthreads();
    float inv = 1.f / (red[0] + red[1] + red[2] + red[3]);
    #pragma unroll
    for (int u = 0; u < 4; ++u) {
        int c = threadIdx.x + u * 256;
        if (c < 1000) out[(size_t)b * 1000 + c] = p[u] * inv;
    }
}

// ---------------- launcher ----------------
extern "C" void kernel_launch(void* const* d_in, const int* in_sizes, int n_in,
                              void* d_out, int out_size, void* d_ws, size_t ws_size,
                              hipStream_t stream)
{
    const float* images  = (const float*)d_in[0];
    const float* W_map   = (const float*)d_in[1];
    const float* ct      = (const float*)d_in[2];
    const float* pos     = (const float*)d_in[3];
    const float* ln1_w   = (const float*)d_in[4];
    const float* ln1_b   = (const float*)d_in[5];
    const float* qkv_w   = (const float*)d_in[6];
    const float* merge_w = (const float*)d_in[7];
    const float* ln2_w   = (const float*)d_in[8];
    const float* ln2_b   = (const float*)d_in[9];
    const float* mlp_w1  = (const float*)d_in[10];
    const float* mlp_b1  = (const float*)d_in[11];
    const float* mlp_w2  = (const float*)d_in[12];
    const float* mlp_b2  = (const float*)d_in[13];
    const float* head_w  = (const float*)d_in[14];
    const float* head_b  = (const float*)d_in[15];
    float* out = (float*)d_out;

    float* ws = (float*)d_ws;
    const size_t XE   = (size_t)ROWS * DIM;
    const size_t PLND = (size_t)MPAD * DIM;    // activation plane (DIM wide)
    const size_t GPL  = (size_t)MPAD * MLPD;   // gelu plane (MLPD wide)

    float* x = ws;
    unsigned short* hh = (unsigned short*)(x + XE);
    unsigned short* hl = hh + PLND;
    unsigned short* oh = hl + PLND;
    unsigned short* ol = oh + PLND;
    unsigned short* gh = ol + PLND;
    unsigned short* gl = gh + GPL;

    // aliases on g region (lifetimes disjoint)
    const size_t PL = (size_t)BHN * PSTR * 64;         // q/k/v packed planes
    unsigned int* qpl = (unsigned int*)gh;             // live qkv->attn
    unsigned int* kpl = qpl + PL;
    unsigned int* vtp = kpl + PL;
    unsigned short* pph = gh;                          // patches live pre-loop
    unsigned short* ppl = pph + PLND;                  // MPAD spacing (over-read safe)

    // weight hi/lo planes after gl
    unsigned short* wb = gl + GPL;
    const size_t qkvE = (size_t)DIM * 2304;
    const size_t mgE  = (size_t)DIM * DIM;
    const size_t m1E  = (size_t)DIM * MLPD;
    const size_t m2E  = (size_t)MLPD * DIM;
    unsigned short* qh  = wb;
    unsigned short* ql  = qh  + qkvE;
    unsigned short* mh  = ql  + qkvE;
    unsigned short* ml  = mh  + mgE;
    unsigned short* h1  = ml  + mgE;
    unsigned short* l1  = h1  + m1E;
    unsigned short* h2  = l1  + m1E;
    unsigned short* l2  = h2  + m2E;
    unsigned short* wmh = l2  + m2E;
    unsigned short* wml = wmh + mgE;

    patchify_kernel<<<(PROWS * DIM + 255) / 256, 256, 0, stream>>>(images, pph, ppl);
    class_pos_kernel<<<(NIMG * DIM + 255) / 256, 256, 0, stream>>>(ct, pos, x);
    convert_one<<<(DIM * (DIM / 32) + 255) / 256, 256, 0, stream>>>(W_map, wmh, wml, DIM, DIM);

    const int gme = 49;  // embed: 49*128 = 6272 = PROWS
    mgemm<1><<<gme * 6, 256, 0, stream>>>(
        pph, ppl, wmh, wml, x, PROWS, DIM, DIM, gme, 6,
        nullptr, nullptr, pos, nullptr, nullptr, nullptr, nullptr, nullptr);

    const int gm = 50;   // 128-row tiles: 50*128 = 6400 = MPAD
    for (int l = 0; l < 12; ++l) {
        convert_layer<<<dim3(288, 4), 256, 0, stream>>>(
            qkv_w + (size_t)l * qkvE, merge_w + (size_t)l * mgE,
            mlp_w1 + (size_t)l * m1E, mlp_w2 + (size_t)l * m2E,
            qh, ql, mh, ml, h1, l1, h2, l2);
        ln_kernel<<<(ROWS + 3) / 4, 256, 0, stream>>>(x, ln1_w + l * DIM, ln1_b + l * DIM, hh, hl, ROWS);
        mgemm<2><<<gm * 18, 256, 0, stream>>>(
            hh, hl, qh, ql, nullptr, ROWS, 2304, DIM, gm, 18,
            nullptr, nullptr, nullptr, qpl, kpl, vtp, nullptr, nullptr);
        attn_mfma<<<dim3(4, BHN), 256, 0, stream>>>(qpl, kpl, vtp, oh, ol);
        mgemm<4><<<gm * 6, 256, 0, stream>>>(
            oh, ol, mh, ml, x, ROWS, DIM, DIM, gm, 6,
            nullptr, x, nullptr, nullptr, nullptr, nullptr, nullptr, nullptr);
        ln_kernel<<<(ROWS + 3) / 4, 256, 0, stream>>>(x, ln2_w + l * DIM, ln2_b + l * DIM, hh, hl, ROWS);
        mgemm<3><<<gm * 24, 256, 0, stream>>>(
            hh, hl, h1, l1, nullptr, ROWS, MLPD, DIM, gm, 24,
            mlp_b1 + (size_t)l * MLPD, nullptr, nullptr, nullptr, nullptr, nullptr, gh, gl);
        mgemm<5><<<gm * 6, 256, 0, stream>>>(
            gh, gl, h2, l2, x, ROWS, DIM, MLPD, gm, 6,
            mlp_b2 + (size_t)l * DIM, x, nullptr, nullptr, nullptr, nullptr, nullptr, nullptr);
    }
    head_kernel<<<NIMG, 256, 0, stream>>>(x, head_w, head_b, out);
}

// Round 13
// 6065.461 us; speedup vs baseline: 1.4606x; 1.4606x over previous
//
#include <hip/hip_runtime.h>
#include <math.h>

// ---------------- constants ----------------
#define NIMG 32
#define NP2  196        // patches per image
#define PTOK 197        // tokens per image
#define DIM  768
#define NH   12
#define VD   64
#define MLPD 3072
#define ROWS (NIMG*PTOK)   // 6304
#define PROWS (NIMG*NP2)   // 6272
#define MPAD 6400          // padded rows for activation planes (glds over-read)
#define PSTR 208           // padded token stride for q/k/v planes
#define BHN (NIMG*NH)      // 384

typedef float f32x4 __attribute__((ext_vector_type(4)));
typedef short bf16x8 __attribute__((ext_vector_type(8)));
typedef unsigned short u16x8 __attribute__((ext_vector_type(8)));
typedef unsigned short u16x4 __attribute__((ext_vector_type(4)));

__device__ __forceinline__ unsigned short f2bf(float x) {
    unsigned int u = __float_as_uint(x);
    return (unsigned short)((u + 0x7FFFu + ((u >> 16) & 1u)) >> 16);
}
__device__ __forceinline__ float bfhi(unsigned short h) {
    return __uint_as_float(((unsigned int)h) << 16);
}
// async global->LDS, 16B per lane; LDS dest = wave base + lane*16 (linear)
__device__ __forceinline__ void glds16(const unsigned short* g, unsigned short* l) {
    __builtin_amdgcn_global_load_lds(
        (const __attribute__((address_space(1))) unsigned int*)g,
        (__attribute__((address_space(3))) unsigned int*)l, 16, 0, 0);
}

// ---------------- patchify -> hi/lo bf16 planes ----------------
__global__ __launch_bounds__(256) void patchify_kernel(const float* __restrict__ img,
                                                       unsigned short* __restrict__ ph,
                                                       unsigned short* __restrict__ pl)
{
    int idx = blockIdx.x * 256 + threadIdx.x;
    if (idx >= PROWS * DIM) return;
    int row = idx / DIM, kk = idx % DIM;
    int b = row / NP2, p = row % NP2;
    int i = p / 14, j = p % 14;
    int c = kk >> 8, r = kk & 255;
    int pr = r >> 4, pw = r & 15;
    float v = img[(((size_t)b*3 + c)*224 + i*16 + pr)*224 + j*16 + pw];
    unsigned short hi = f2bf(v);
    ph[idx] = hi;
    pl[idx] = f2bf(v - bfhi(hi));
}

// ---------------- class token + pos row0 ----------------
__global__ __launch_bounds__(256) void class_pos_kernel(const float* __restrict__ ct,
                                                        const float* __restrict__ pos,
                                                        float* __restrict__ x)
{
    int idx = blockIdx.x * 256 + threadIdx.x;
    if (idx >= NIMG * DIM) return;
    int b = idx / DIM, d = idx % DIM;
    x[(size_t)b * PTOK * DIM + d] = ct[d] + pos[d];
}

// ---------------- weight conversion: W[K][N] fp32 -> blocked hi/lo bf16 ----------------
// Blocked: [N/128][K/32][128][32] row-major (n_in, k_in), 4096 elems / 8KB per block.
__device__ __forceinline__ void conv_body(const float* __restrict__ W,
    unsigned short* __restrict__ Bh, unsigned short* __restrict__ Bl, int K, int N)
{
    int idx = blockIdx.x * 256 + threadIdx.x;
    if (idx >= N * (K >> 5)) return;
    int kb = idx / N;
    int n  = idx - kb * N;
    size_t off = (((size_t)(n >> 7) * (K >> 5) + kb) * 128 + (n & 127)) * 32;
    #pragma unroll
    for (int u = 0; u < 4; ++u) {
        u16x8 h, l;
        #pragma unroll
        for (int j = 0; j < 8; ++j) {
            float x = W[(size_t)(kb * 32 + u * 8 + j) * N + n];
            unsigned short hh = f2bf(x);
            h[j] = hh;
            l[j] = f2bf(x - bfhi(hh));
        }
        *(u16x8*)&Bh[off + u * 8] = h;
        *(u16x8*)&Bl[off + u * 8] = l;
    }
}

__global__ __launch_bounds__(256) void convert_one(const float* __restrict__ W,
    unsigned short* __restrict__ Bh, unsigned short* __restrict__ Bl, int K, int N)
{
    conv_body(W, Bh, Bl, K, N);
}

__global__ __launch_bounds__(256) void convert_layer(
    const float* __restrict__ qw, const float* __restrict__ mw,
    const float* __restrict__ w1, const float* __restrict__ w2,
    unsigned short* qh, unsigned short* ql, unsigned short* mh, unsigned short* ml,
    unsigned short* h1, unsigned short* l1, unsigned short* h2, unsigned short* l2)
{
    switch (blockIdx.y) {
        case 0: conv_body(qw, qh, ql, DIM, 3*NH*VD); break;
        case 1: conv_body(mw, mh, ml, DIM, DIM);     break;
        case 2: conv_body(w1, h1, l1, DIM, MLPD);    break;
        case 3: conv_body(w2, h2, l2, MLPD, DIM);    break;
    }
}

// ---------------- shared epilogue ----------------
template<int MODE>
__device__ __forceinline__ void epi_store(
    int r, int c, float val, float* __restrict__ C, int M, int N,
    const float* __restrict__ bias, const float* __restrict__ res,
    const float* __restrict__ pos,
    unsigned int* __restrict__ qo, unsigned int* __restrict__ ko, unsigned int* __restrict__ vo,
    unsigned short* __restrict__ oph, unsigned short* __restrict__ opl)
{
    if (MODE == 1) {
        int b = r / NP2, p = r - b * NP2;
        C[((size_t)b * PTOK + 1 + p) * DIM + c] = val + pos[(size_t)(p + 1) * DIM + c];
    } else if (MODE == 2) {
        int b = r / PTOK, p = r - b * PTOK;
        int t = c % 3, hv = c / 3;
        int hd = hv >> 6, vv = hv & 63;
        size_t bh = (size_t)b * NH + hd;
        float sv = (t == 0) ? val * 0.125f : val;
        unsigned short hi = f2bf(sv);
        unsigned short lo = f2bf(sv - bfhi(hi));
        unsigned int w32 = (unsigned int)hi | ((unsigned int)lo << 16);
        if (t == 2) vo[(bh * 64 + vv) * PSTR + p] = w32;
        else if (t == 0) qo[(bh * PSTR + p) * 64 + vv] = w32;
        else ko[(bh * PSTR + p) * 64 + vv] = w32;
    } else if (MODE == 3) {
        float tmp = val + bias[c];
        float gel = 0.5f * tmp * (1.0f + erff(tmp * 0.70710678118654752f));
        unsigned short hi = f2bf(gel);
        oph[(size_t)r * N + c] = hi;
        opl[(size_t)r * N + c] = f2bf(gel - bfhi(hi));
    } else if (MODE == 4) {
        C[(size_t)r * N + c] = res[(size_t)r * N + c] + val;
    } else if (MODE == 5) {
        C[(size_t)r * N + c] = res[(size_t)r * N + c] + val + bias[c];
    }
}

// ---------------- mgemm: 128x128 tile, single 32KB buffer, 4 blocks/CU (r9-exact) ----------------
// Drain-then-compute; latency hidden by TLP (m114 implicit overlap).
// Bijective XCD chunking keeps FETCH at the per-XCD floor (r6: 200->93MB).
// Used for narrow-N GEMMs (merge, MLP2, embed).
// Register budget: 64 VGPR + 64 AGPR(acc) = 128 = (256,4) cap. Do NOT add live regs.
template<int MODE>
__global__ __launch_bounds__(256, 4) void mgemm(
    const unsigned short* __restrict__ Ah, const unsigned short* __restrict__ Al,
    const unsigned short* __restrict__ Bh, const unsigned short* __restrict__ Bl,
    float* __restrict__ C, int M, int N, int K, int gm, int gn,
    const float* __restrict__ bias, const float* __restrict__ res,
    const float* __restrict__ pos,
    unsigned int* __restrict__ qo, unsigned int* __restrict__ ko, unsigned int* __restrict__ vo,
    unsigned short* __restrict__ oph, unsigned short* __restrict__ opl)
{
    __shared__ unsigned short SAh[4096];
    __shared__ unsigned short SAl[4096];
    __shared__ unsigned short SBh[4096];
    __shared__ unsigned short SBl[4096];

    const int tid = threadIdx.x;
    const int nwg = gm * gn;
    const int q = nwg >> 3, r = nwg & 7;
    const int xcd = blockIdx.x & 7, li = blockIdx.x >> 3;
    const int seq = xcd * q + (xcd < r ? xcd : r) + li;
    const int mt = seq / gn, nt = seq - mt * gn;
    const int m0 = mt * 128, n0 = nt * 128;

    const int wave = tid >> 6, lane = tid & 63;
    const int wm = (wave >> 1) * 64, wn = (wave & 1) * 64;
    const int lr = lane & 15, lg = lane >> 4;

    const int r0 = tid >> 2, sl = tid & 3;
    const int s0 = sl ^ ((r0 >> 1) & 3);
    const size_t aoff0 = (size_t)(m0 + r0) * K + s0 * 8;
    const size_t aoff1 = (size_t)(m0 + r0 + 64) * K + s0 * 8;
    const size_t boff0 = (size_t)(n0 >> 7) * (K >> 5) * 4096 + (size_t)r0 * 32 + s0 * 8;

    int aro[4], bro[4];
    #pragma unroll
    for (int i = 0; i < 4; ++i) {
        int rowA = wm + i * 16 + lr;
        aro[i] = rowA * 32 + ((lg ^ ((rowA >> 1) & 3)) * 8);
        int rowB = wn + i * 16 + lr;
        bro[i] = rowB * 32 + ((lg ^ ((rowB >> 1) & 3)) * 8);
    }

    f32x4 acc[4][4];
    #pragma unroll
    for (int i = 0; i < 4; ++i)
        #pragma unroll
        for (int j = 0; j < 4; ++j)
            #pragma unroll
            for (int e = 0; e < 4; ++e) acc[i][j][e] = 0.f;

    const int kSteps = K >> 5;
    #pragma unroll 1
    for (int ks = 0; ks < kSteps; ++ks) {
        __syncthreads();                 // prev frag reads done
        const size_t ak = (size_t)ks * 32;
        const size_t bk = (size_t)ks * 4096;
        glds16(Ah + aoff0 + ak, SAh + tid * 8);
        glds16(Ah + aoff1 + ak, SAh + 2048 + tid * 8);
        glds16(Al + aoff0 + ak, SAl + tid * 8);
        glds16(Al + aoff1 + ak, SAl + 2048 + tid * 8);
        glds16(Bh + boff0 + bk, SBh + tid * 8);
        glds16(Bh + boff0 + bk + 2048, SBh + 2048 + tid * 8);
        glds16(Bl + boff0 + bk, SBl + tid * 8);
        glds16(Bl + boff0 + bk + 2048, SBl + 2048 + tid * 8);
        __syncthreads();                 // drains vmcnt before barrier

        bf16x8 bfh[4], bfl[4];
        #pragma unroll
        for (int ni = 0; ni < 4; ++ni) {
            bfh[ni] = *(const bf16x8*)&SBh[bro[ni]];
            bfl[ni] = *(const bf16x8*)&SBl[bro[ni]];
        }
        #pragma unroll
        for (int mi = 0; mi < 4; ++mi) {
            bf16x8 afh = *(const bf16x8*)&SAh[aro[mi]];
            bf16x8 afl = *(const bf16x8*)&SAl[aro[mi]];
            #pragma unroll
            for (int ni = 0; ni < 4; ++ni) {
                acc[mi][ni] = __builtin_amdgcn_mfma_f32_16x16x32_bf16(afh, bfh[ni], acc[mi][ni], 0, 0, 0);
                acc[mi][ni] = __builtin_amdgcn_mfma_f32_16x16x32_bf16(afh, bfl[ni], acc[mi][ni], 0, 0, 0);
                acc[mi][ni] = __builtin_amdgcn_mfma_f32_16x16x32_bf16(afl, bfh[ni], acc[mi][ni], 0, 0, 0);
            }
        }
    }

    #pragma unroll
    for (int mi = 0; mi < 4; ++mi) {
        #pragma unroll
        for (int ni = 0; ni < 4; ++ni) {
            f32x4 v = acc[mi][ni];
            int c = n0 + wn + ni * 16 + lr;
            #pragma unroll
            for (int rr = 0; rr < 4; ++rr) {
                int rr2 = m0 + wm + mi * 16 + lg * 4 + rr;
                if (rr2 >= M) continue;
                epi_store<MODE>(rr2, c, v[rr], C, M, N, bias, res, pos, qo, ko, vo, oph, opl);
            }
        }
    }
}

// ---------------- mgemmw: 256x128 block, 4 waves of 128x64, 48KB LDS, 2 blocks/CU ----------------
// r12 model closure: 128^2 runs exactly at its structural bound (0.375->0.5 KB LDS/MFMA).
// This tile raises MFMA-per-LDS-byte 33% (96KB reads+48KB writes per 384 MFMA).
// Same r9 drain schedule (r7/r8: explicit pipelines lose to TLP at these sizes).
// Registers: acc 8x4 f32x4 = 128 + ~70 VGPR ~= 200 -> (256,2) = 256-reg cap (no spill;
// r5/r10 spill signature = low VGPR_Count + GB-scale WRITE_SIZE).
// Used for wide-N GEMMs only (qkv 450 blocks, MLP1 600 blocks: no tail quantization).
template<int MODE>
__global__ __launch_bounds__(256, 2) void mgemmw(
    const unsigned short* __restrict__ Ah, const unsigned short* __restrict__ Al,
    const unsigned short* __restrict__ Bh, const unsigned short* __restrict__ Bl,
    float* __restrict__ C, int M, int N, int K, int gm, int gn,
    const float* __restrict__ bias, const float* __restrict__ res,
    const float* __restrict__ pos,
    unsigned int* __restrict__ qo, unsigned int* __restrict__ ko, unsigned int* __restrict__ vo,
    unsigned short* __restrict__ oph, unsigned short* __restrict__ opl)
{
    __shared__ unsigned short SAh[8192];   // 256 rows x 32
    __shared__ unsigned short SAl[8192];
    __shared__ unsigned short SBh[4096];   // 128 rows x 32
    __shared__ unsigned short SBl[4096];

    const int tid = threadIdx.x;
    const int nwg = gm * gn;
    const int q = nwg >> 3, r = nwg & 7;
    const int xcd = blockIdx.x & 7, li = blockIdx.x >> 3;
    const int seq = xcd * q + (xcd < r ? xcd : r) + li;
    const int mt = seq / gn, nt = seq - mt * gn;
    const int m0 = mt * 256, n0 = nt * 128;

    const int wave = tid >> 6, lane = tid & 63;
    const int wm = (wave >> 1) * 128, wn = (wave & 1) * 64;   // wave tile 128x64
    const int lr = lane & 15, lg = lane >> 4;

    const int r0 = tid >> 2, sl = tid & 3;
    const int s0 = sl ^ ((r0 >> 1) & 3);       // f(r0+64n)==f(r0)
    const size_t aoff0 = (size_t)(m0 + r0) * K + s0 * 8;
    const size_t aoff1 = (size_t)(m0 + r0 + 64) * K + s0 * 8;
    const size_t aoff2 = (size_t)(m0 + r0 + 128) * K + s0 * 8;
    const size_t aoff3 = (size_t)(m0 + r0 + 192) * K + s0 * 8;
    const size_t boff0 = (size_t)(n0 >> 7) * (K >> 5) * 4096 + (size_t)r0 * 32 + s0 * 8;

    int aro[8], bro[4];
    #pragma unroll
    for (int i = 0; i < 8; ++i) {
        int rowA = wm + i * 16 + lr;
        aro[i] = rowA * 32 + ((lg ^ ((rowA >> 1) & 3)) * 8);
    }
    #pragma unroll
    for (int i = 0; i < 4; ++i) {
        int rowB = wn + i * 16 + lr;
        bro[i] = rowB * 32 + ((lg ^ ((rowB >> 1) & 3)) * 8);
    }

    f32x4 acc[8][4];
    #pragma unroll
    for (int i = 0; i < 8; ++i)
        #pragma unroll
        for (int j = 0; j < 4; ++j)
            #pragma unroll
            for (int e = 0; e < 4; ++e) acc[i][j][e] = 0.f;

    const int kSteps = K >> 5;
    #pragma unroll 1
    for (int ks = 0; ks < kSteps; ++ks) {
        __syncthreads();                 // prev frag reads done
        const size_t ak = (size_t)ks * 32;
        const size_t bk = (size_t)ks * 4096;
        glds16(Ah + aoff0 + ak, SAh + tid * 8);
        glds16(Ah + aoff1 + ak, SAh + 2048 + tid * 8);
        glds16(Ah + aoff2 + ak, SAh + 4096 + tid * 8);
        glds16(Ah + aoff3 + ak, SAh + 6144 + tid * 8);
        glds16(Al + aoff0 + ak, SAl + tid * 8);
        glds16(Al + aoff1 + ak, SAl + 2048 + tid * 8);
        glds16(Al + aoff2 + ak, SAl + 4096 + tid * 8);
        glds16(Al + aoff3 + ak, SAl + 6144 + tid * 8);
        glds16(Bh + boff0 + bk, SBh + tid * 8);
        glds16(Bh + boff0 + bk + 2048, SBh + 2048 + tid * 8);
        glds16(Bl + boff0 + bk, SBl + tid * 8);
        glds16(Bl + boff0 + bk + 2048, SBl + 2048 + tid * 8);
        __syncthreads();                 // drains vmcnt before barrier

        bf16x8 bfh[4], bfl[4];
        #pragma unroll
        for (int ni = 0; ni < 4; ++ni) {
            bfh[ni] = *(const bf16x8*)&SBh[bro[ni]];
            bfl[ni] = *(const bf16x8*)&SBl[bro[ni]];
        }
        #pragma unroll
        for (int mi = 0; mi < 8; ++mi) {
            bf16x8 afh = *(const bf16x8*)&SAh[aro[mi]];
            bf16x8 afl = *(const bf16x8*)&SAl[aro[mi]];
            #pragma unroll
            for (int ni = 0; ni < 4; ++ni) {
                acc[mi][ni] = __builtin_amdgcn_mfma_f32_16x16x32_bf16(afh, bfh[ni], acc[mi][ni], 0, 0, 0);
                acc[mi][ni] = __builtin_amdgcn_mfma_f32_16x16x32_bf16(afh, bfl[ni], acc[mi][ni], 0, 0, 0);
                acc[mi][ni] = __builtin_amdgcn_mfma_f32_16x16x32_bf16(afl, bfh[ni], acc[mi][ni], 0, 0, 0);
            }
        }
    }

    #pragma unroll
    for (int mi = 0; mi < 8; ++mi) {
        #pragma unroll
        for (int ni = 0; ni < 4; ++ni) {
            f32x4 v = acc[mi][ni];
            int c = n0 + wn + ni * 16 + lr;
            #pragma unroll
            for (int rr = 0; rr < 4; ++rr) {
                int rr2 = m0 + wm + mi * 16 + lg * 4 + rr;
                if (rr2 >= M) continue;
                epi_store<MODE>(rr2, c, v[rr], C, M, N, bias, res, pos, qo, ko, vo, oph, opl);
            }
        }
    }
}

// ---------------- LayerNorm -> hi/lo bf16 planes ----------------
__global__ __launch_bounds__(256) void ln_kernel(const float* __restrict__ x,
                                                 const float* __restrict__ w,
                                                 const float* __restrict__ b,
                                                 unsigned short* __restrict__ oh,
                                                 unsigned short* __restrict__ ol, int rows)
{
    int wave = threadIdx.x >> 6, lane = threadIdx.x & 63;
    int row = blockIdx.x * 4 + wave;
    if (row >= rows) return;
    const float* xr = x + (size_t)row * DIM;
    float vals[12];
    float sum = 0.f;
    #pragma unroll
    for (int u = 0; u < 12; ++u) { vals[u] = xr[u * 64 + lane]; sum += vals[u]; }
    #pragma unroll
    for (int off = 32; off; off >>= 1) sum += __shfl_xor(sum, off);
    float mean = sum * (1.f / DIM);
    float vs = 0.f;
    #pragma unroll
    for (int u = 0; u < 12; ++u) { float d = vals[u] - mean; vs += d * d; }
    #pragma unroll
    for (int off = 32; off; off >>= 1) vs += __shfl_xor(vs, off);
    float rstd = rsqrtf(vs * (1.f / DIM) + 1e-5f);
    #pragma unroll
    for (int u = 0; u < 12; ++u) {
        int d = u * 64 + lane;
        float v = (vals[u] - mean) * rstd * w[d] + b[d];
        unsigned short hi = f2bf(v);
        oh[(size_t)row * DIM + d] = hi;
        ol[(size_t)row * DIM + d] = f2bf(v - bfhi(hi));
    }
}

// ---------------- MFMA attention (epilogue -> hi/lo planes) ----------------
__global__ __launch_bounds__(256) void attn_mfma(
    const unsigned int* __restrict__ qp, const unsigned int* __restrict__ kp,
    const unsigned int* __restrict__ vtp,
    unsigned short* __restrict__ oh, unsigned short* __restrict__ ol)
{
    __shared__ unsigned short KVh[64 * 72];
    __shared__ unsigned short KVl[64 * 72];
    __shared__ unsigned short Ph[64 * 72];
    __shared__ unsigned short Pl[64 * 72];

    const int tid = threadIdx.x;
    const int w = tid >> 6, lane = tid & 63;
    const int l = lane & 15, g = lane >> 4;
    const int bh = blockIdx.y, q0 = blockIdx.x * 64;
    const int b = bh / NH, hd = bh - b * NH;

    int qrow = q0 + 16 * w + l;
    if (qrow >= PTOK) qrow = 0;
    const unsigned int* qbase = qp + ((size_t)bh * PSTR + qrow) * 64;
    bf16x8 qAh[2], qAl[2];
    #pragma unroll
    for (int ks = 0; ks < 2; ++ks) {
        const unsigned int* p = qbase + 32 * ks + 8 * g;
        uint4 a = *(const uint4*)p;
        uint4 c = *(const uint4*)(p + 4);
        bf16x8 h8, l8;
        h8[0]=(short)a.x; h8[1]=(short)a.y; h8[2]=(short)a.z; h8[3]=(short)a.w;
        h8[4]=(short)c.x; h8[5]=(short)c.y; h8[6]=(short)c.z; h8[7]=(short)c.w;
        l8[0]=(short)(a.x>>16); l8[1]=(short)(a.y>>16); l8[2]=(short)(a.z>>16); l8[3]=(short)(a.w>>16);
        l8[4]=(short)(c.x>>16); l8[5]=(short)(c.y>>16); l8[6]=(short)(c.z>>16); l8[7]=(short)(c.w>>16);
        qAh[ks] = h8; qAl[ks] = l8;
    }

    f32x4 s[13];
    #pragma unroll
    for (int t = 0; t < 13; ++t)
        #pragma unroll
        for (int e = 0; e < 4; ++e) s[t][e] = 0.f;

    for (int c = 0; c < 4; ++c) {
        __syncthreads();
        const int rows = (c < 3) ? 64 : 16;
        for (int u = tid; u < rows * 16; u += 256) {
            int r = u >> 4, cc = u & 15;
            int j = c * 64 + r;
            uint4 wv = make_uint4(0, 0, 0, 0);
            if (j < PTOK) wv = *(const uint4*)(kp + ((size_t)bh * PSTR + j) * 64 + cc * 4);
            u16x4 h4, l4;
            h4[0]=(unsigned short)wv.x; h4[1]=(unsigned short)wv.y;
            h4[2]=(unsigned short)wv.z; h4[3]=(unsigned short)wv.w;
            l4[0]=(unsigned short)(wv.x>>16); l4[1]=(unsigned short)(wv.y>>16);
            l4[2]=(unsigned short)(wv.z>>16); l4[3]=(unsigned short)(wv.w>>16);
            *(u16x4*)&KVh[r * 72 + cc * 4] = h4;
            *(u16x4*)&KVl[r * 72 + cc * 4] = l4;
        }
        __syncthreads();
        const int tc = (c < 3) ? 4 : 1;
        for (int t = 0; t < tc; ++t) {
            int ti = c * 4 + t;
            #pragma unroll
            for (int ks = 0; ks < 2; ++ks) {
                bf16x8 kh = *(const bf16x8*)&KVh[(16 * t + l) * 72 + 32 * ks + 8 * g];
                bf16x8 kl = *(const bf16x8*)&KVl[(16 * t + l) * 72 + 32 * ks + 8 * g];
                s[ti] = __builtin_amdgcn_mfma_f32_16x16x32_bf16(qAh[ks], kh, s[ti], 0, 0, 0);
                s[ti] = __builtin_amdgcn_mfma_f32_16x16x32_bf16(qAh[ks], kl, s[ti], 0, 0, 0);
                s[ti] = __builtin_amdgcn_mfma_f32_16x16x32_bf16(qAl[ks], kh, s[ti], 0, 0, 0);
            }
        }
    }

    if (l >= 5) {
        #pragma unroll
        for (int e = 0; e < 4; ++e) s[12][e] = -1e30f;
    }

    float mx[4], rs[4];
    #pragma unroll
    for (int e = 0; e < 4; ++e) {
        float m = s[0][e];
        #pragma unroll
        for (int t = 1; t < 13; ++t) m = fmaxf(m, s[t][e]);
        #pragma unroll
        for (int off = 1; off < 16; off <<= 1) m = fmaxf(m, __shfl_xor(m, off));
        mx[e] = m;
    }
    #pragma unroll
    for (int e = 0; e < 4; ++e) {
        float sum = 0.f;
        #pragma unroll
        for (int t = 0; t < 13; ++t) {
            float p = __expf(s[t][e] - mx[e]);
            s[t][e] = p;
            sum += p;
        }
        #pragma unroll
        for (int off = 1; off < 16; off <<= 1) sum += __shfl_xor(sum, off);
        rs[e] = 1.f / sum;
    }

    f32x4 o[4];
    #pragma unroll
    for (int t = 0; t < 4; ++t)
        #pragma unroll
        for (int e = 0; e < 4; ++e) o[t][e] = 0.f;

    for (int c = 0; c < 4; ++c) {
        __syncthreads();
        const int cols = (c < 3) ? 64 : 32;
        const int cpr = cols >> 2;
        for (int u = tid; u < 64 * cpr; u += 256) {
            int r = u / cpr, cc = u % cpr;
            int jbase = c * 64 + cc * 4;
            uint4 wv;
            if (c < 3) {
                wv = *(const uint4*)(vtp + ((size_t)bh * 64 + r) * PSTR + jbase);
            } else {
                unsigned int t0 = (jbase + 0 < PTOK) ? vtp[((size_t)bh * 64 + r) * PSTR + jbase + 0] : 0u;
                unsigned int t1 = (jbase + 1 < PTOK) ? vtp[((size_t)bh * 64 + r) * PSTR + jbase + 1] : 0u;
                unsigned int t2 = (jbase + 2 < PTOK) ? vtp[((size_t)bh * 64 + r) * PSTR + jbase + 2] : 0u;
                unsigned int t3 = (jbase + 3 < PTOK) ? vtp[((size_t)bh * 64 + r) * PSTR + jbase + 3] : 0u;
                wv = make_uint4(t0, t1, t2, t3);
            }
            u16x4 h4, l4;
            h4[0]=(unsigned short)wv.x; h4[1]=(unsigned short)wv.y;
            h4[2]=(unsigned short)wv.z; h4[3]=(unsigned short)wv.w;
            l4[0]=(unsigned short)(wv.x>>16); l4[1]=(unsigned short)(wv.y>>16);
            l4[2]=(unsigned short)(wv.z>>16); l4[3]=(unsigned short)(wv.w>>16);
            *(u16x4*)&KVh[r * 72 + cc * 4] = h4;
            *(u16x4*)&KVl[r * 72 + cc * 4] = l4;
        }
        const int tc = (c < 3) ? 4 : 1;
        for (int t = 0; t < tc; ++t) {
            int ti = c * 4 + t;
            #pragma unroll
            for (int e = 0; e < 4; ++e) {
                int row = 16 * w + 4 * g + e, col = 16 * t + l;
                float pv = s[ti][e];
                unsigned short hi = f2bf(pv);
                Ph[row * 72 + col] = hi;
                Pl[row * 72 + col] = f2bf(pv - bfhi(hi));
            }
        }
        __syncthreads();
        const int ksn = (c < 3) ? 2 : 1;
        for (int ks = 0; ks < ksn; ++ks) {
            bf16x8 pa_h = *(const bf16x8*)&Ph[(16 * w + l) * 72 + 32 * ks + 8 * g];
            bf16x8 pa_l = *(const bf16x8*)&Pl[(16 * w + l) * 72 + 32 * ks + 8 * g];
            #pragma unroll
            for (int tv = 0; tv < 4; ++tv) {
                bf16x8 vh = *(const bf16x8*)&KVh[(16 * tv + l) * 72 + 32 * ks + 8 * g];
                bf16x8 vl = *(const bf16x8*)&KVl[(16 * tv + l) * 72 + 32 * ks + 8 * g];
                o[tv] = __builtin_amdgcn_mfma_f32_16x16x32_bf16(pa_h, vh, o[tv], 0, 0, 0);
                o[tv] = __builtin_amdgcn_mfma_f32_16x16x32_bf16(pa_h, vl, o[tv], 0, 0, 0);
                o[tv] = __builtin_amdgcn_mfma_f32_16x16x32_bf16(pa_l, vh, o[tv], 0, 0, 0);
            }
        }
    }

    #pragma unroll
    for (int tv = 0; tv < 4; ++tv) {
        #pragma unroll
        for (int e = 0; e < 4; ++e) {
            int q = q0 + 16 * w + 4 * g + e;
            if (q < PTOK) {
                float v = o[tv][e] * rs[e];
                size_t idx = ((size_t)(b * PTOK + q)) * DIM + hd * 64 + 16 * tv + l;
                unsigned short hi = f2bf(v);
                oh[idx] = hi;
                ol[idx] = f2bf(v - bfhi(hi));
            }
        }
    }
}

// ---------------- head: logits + softmax ----------------
__global__ __launch_bounds__(256) void head_kernel(const float* __restrict__ x,
                                                   const float* __restrict__ W,
                                                   const float* __restrict__ bias,
                                                   float* __restrict__ out)
{
    __shared__ __align__(16) float xl[DIM];
    __shared__ float red[4];
    int b = blockIdx.x;
    const float* xr = x + (size_t)b * PTOK * DIM;
    for (int idx = threadIdx.x; idx < DIM; idx += 256) xl[idx] = xr[idx];
    __syncthreads();

    float logit[4];
    #pragma unroll
    for (int u = 0; u < 4; ++u) {
        int c = threadIdx.x + u * 256;
        float acc = (c < 1000) ? bias[c] : -INFINITY;
        if (c < 1000) {
            for (int k = 0; k < DIM; k += 4) {
                float4 xv = *(const float4*)&xl[k];
                acc += xv.x * W[(size_t)k * 1000 + c]
                     + xv.y * W[(size_t)(k + 1) * 1000 + c]
                     + xv.z * W[(size_t)(k + 2) * 1000 + c]
                     + xv.w * W[(size_t)(k + 3) * 1000 + c];
            }
        }
        logit[u] = acc;
    }
    int lane = threadIdx.x & 63, wv = threadIdx.x >> 6;
    float m = fmaxf(fmaxf(logit[0], logit[1]), fmaxf(logit[2], logit[3]));
    #pragma unroll
    for (int off = 32; off; off >>= 1) m = fmaxf(m, __shfl_xor(m, off));
    if (lane == 0) red[wv] = m;
    __syncthreads();
    m = fmaxf(fmaxf(red[0], red[1]), fmaxf(red[2], red[3]));

    float p[4]; float sum = 0.f;
    #pragma unroll
    for (int u = 0; u < 4; ++u) {
        int c = threadIdx.x + u * 256;
        p[u] = (c < 1000) ? expf(logit[u] - m) : 0.f;
        sum += p[u];
    }
    #pragma unroll
    for (int off = 32; off; off >>= 1) sum += __shfl_xor(sum, off);
    __syncthreads();
    if (lane == 0) red[wv] = sum;
    __syncthreads();
    float inv = 1.f / (red[0] + red[1] + red[2] + red[3]);
    #pragma unroll
    for (int u = 0; u < 4; ++u) {
        int c = threadIdx.x + u * 256;
        if (c < 1000) out[(size_t)b * 1000 + c] = p[u] * inv;
    }
}

// ---------------- launcher ----------------
extern "C" void kernel_launch(void* const* d_in, const int* in_sizes, int n_in,
                              void* d_out, int out_size, void* d_ws, size_t ws_size,
                              hipStream_t stream)
{
    const float* images  = (const float*)d_in[0];
    const float* W_map   = (const float*)d_in[1];
    const float* ct      = (const float*)d_in[2];
    const float* pos     = (const float*)d_in[3];
    const float* ln1_w   = (const float*)d_in[4];
    const float* ln1_b   = (const float*)d_in[5];
    const float* qkv_w   = (const float*)d_in[6];
    const float* merge_w = (const float*)d_in[7];
    const float* ln2_w   = (const float*)d_in[8];
    const float* ln2_b   = (const float*)d_in[9];
    const float* mlp_w1  = (const float*)d_in[10];
    const float* mlp_b1  = (const float*)d_in[11];
    const float* mlp_w2  = (const float*)d_in[12];
    const float* mlp_b2  = (const float*)d_in[13];
    const float* head_w  = (const float*)d_in[14];
    const float* head_b  = (const float*)d_in[15];
    float* out = (float*)d_out;

    float* ws = (float*)d_ws;
    const size_t XE   = (size_t)ROWS * DIM;
    const size_t PLND = (size_t)MPAD * DIM;    // activation plane (DIM wide)
    const size_t GPL  = (size_t)MPAD * MLPD;   // gelu plane (MLPD wide)

    float* x = ws;
    unsigned short* hh = (unsigned short*)(x + XE);
    unsigned short* hl = hh + PLND;
    unsigned short* oh = hl + PLND;
    unsigned short* ol = oh + PLND;
    unsigned short* gh = ol + PLND;
    unsigned short* gl = gh + GPL;

    // aliases on g region (lifetimes disjoint)
    const size_t PL = (size_t)BHN * PSTR * 64;         // q/k/v packed planes
    unsigned int* qpl = (unsigned int*)gh;             // live qkv->attn
    unsigned int* kpl = qpl + PL;
    unsigned int* vtp = kpl + PL;
    unsigned short* pph = gh;                          // patches live pre-loop
    unsigned short* ppl = pph + PLND;                  // MPAD spacing (over-read safe)

    // weight hi/lo planes after gl
    unsigned short* wb = gl + GPL;
    const size_t qkvE = (size_t)DIM * 2304;
    const size_t mgE  = (size_t)DIM * DIM;
    const size_t m1E  = (size_t)DIM * MLPD;
    const size_t m2E  = (size_t)MLPD * DIM;
    unsigned short* qh  = wb;
    unsigned short* ql  = qh  + qkvE;
    unsigned short* mh  = ql  + qkvE;
    unsigned short* ml  = mh  + mgE;
    unsigned short* h1  = ml  + mgE;
    unsigned short* l1  = h1  + m1E;
    unsigned short* h2  = l1  + m1E;
    unsigned short* l2  = h2  + m2E;
    unsigned short* wmh = l2  + m2E;
    unsigned short* wml = wmh + mgE;

    patchify_kernel<<<(PROWS * DIM + 255) / 256, 256, 0, stream>>>(images, pph, ppl);
    class_pos_kernel<<<(NIMG * DIM + 255) / 256, 256, 0, stream>>>(ct, pos, x);
    convert_one<<<(DIM * (DIM / 32) + 255) / 256, 256, 0, stream>>>(W_map, wmh, wml, DIM, DIM);

    const int gme = 49;  // embed: 49*128 = 6272 = PROWS
    mgemm<1><<<gme * 6, 256, 0, stream>>>(
        pph, ppl, wmh, wml, x, PROWS, DIM, DIM, gme, 6,
        nullptr, nullptr, pos, nullptr, nullptr, nullptr, nullptr, nullptr);

    const int gm  = 50;  // 128-row tiles: 50*128 = 6400 = MPAD
    const int gmw = 25;  // 256-row tiles: 25*256 = 6400
    for (int l = 0; l < 12; ++l) {
        convert_layer<<<dim3(288, 4), 256, 0, stream>>>(
            qkv_w + (size_t)l * qkvE, merge_w + (size_t)l * mgE,
            mlp_w1 + (size_t)l * m1E, mlp_w2 + (size_t)l * m2E,
            qh, ql, mh, ml, h1, l1, h2, l2);
        ln_kernel<<<(ROWS + 3) / 4, 256, 0, stream>>>(x, ln1_w + l * DIM, ln1_b + l * DIM, hh, hl, ROWS);
        mgemmw<2><<<gmw * 18, 256, 0, stream>>>(
            hh, hl, qh, ql, nullptr, ROWS, 2304, DIM, gmw, 18,
            nullptr, nullptr, nullptr, qpl, kpl, vtp, nullptr, nullptr);
        attn_mfma<<<dim3(4, BHN), 256, 0, stream>>>(qpl, kpl, vtp, oh, ol);
        mgemm<4><<<gm * 6, 256, 0, stream>>>(
            oh, ol, mh, ml, x, ROWS, DIM, DIM, gm, 6,
            nullptr, x, nullptr, nullptr, nullptr, nullptr, nullptr, nullptr);
        ln_kernel<<<(ROWS + 3) / 4, 256, 0, stream>>>(x, ln2_w + l * DIM, ln2_b + l * DIM, hh, hl, ROWS);
        mgemmw<3><<<gmw * 24, 256, 0, stream>>>(
            hh, hl, h1, l1, nullptr, ROWS, MLPD, DIM, gmw, 24,
            mlp_b1 + (size_t)l * MLPD, nullptr, nullptr, nullptr, nullptr, nullptr, gh, gl);
        mgemm<5><<<gm * 6, 256, 0, stream>>>(
            gh, gl, h2, l2, x, ROWS, DIM, MLPD, gm, 6,
            mlp_b2 + (size_t)l * DIM, x, nullptr, nullptr, nullptr, nullptr, nullptr, nullptr);
    }
    head_kernel<<<NIMG, 256, 0, stream>>>(x, head_w, head_b, out);
}

// Round 14
// 5671.676 us; speedup vs baseline: 1.5620x; 1.0694x over previous
//
#include <hip/hip_runtime.h>
#include <math.h>

// ---------------- constants ----------------
#define NIMG 32
#define NP2  196        // patches per image
#define PTOK 197        // tokens per image
#define DIM  768
#define NH   12
#define VD   64
#define MLPD 3072
#define ROWS (NIMG*PTOK)   // 6304
#define PROWS (NIMG*NP2)   // 6272
#define MPAD 6400          // padded rows for activation planes (glds over-read)
#define PSTR 208           // padded token stride for q/k/v planes
#define BHN (NIMG*NH)      // 384

typedef float f32x4 __attribute__((ext_vector_type(4)));
typedef short bf16x8 __attribute__((ext_vector_type(8)));
typedef unsigned short u16x8 __attribute__((ext_vector_type(8)));
typedef unsigned short u16x4 __attribute__((ext_vector_type(4)));

__device__ __forceinline__ unsigned short f2bf(float x) {
    unsigned int u = __float_as_uint(x);
    return (unsigned short)((u + 0x7FFFu + ((u >> 16) & 1u)) >> 16);
}
__device__ __forceinline__ float bfhi(unsigned short h) {
    return __uint_as_float(((unsigned int)h) << 16);
}
// async global->LDS, 16B per lane; LDS dest = wave base + lane*16 (linear)
__device__ __forceinline__ void glds16(const unsigned short* g, unsigned short* l) {
    __builtin_amdgcn_global_load_lds(
        (const __attribute__((address_space(1))) unsigned int*)g,
        (__attribute__((address_space(3))) unsigned int*)l, 16, 0, 0);
}

// ---------------- patchify -> hi/lo bf16 planes ----------------
__global__ __launch_bounds__(256) void patchify_kernel(const float* __restrict__ img,
                                                       unsigned short* __restrict__ ph,
                                                       unsigned short* __restrict__ pl)
{
    int idx = blockIdx.x * 256 + threadIdx.x;
    if (idx >= PROWS * DIM) return;
    int row = idx / DIM, kk = idx % DIM;
    int b = row / NP2, p = row % NP2;
    int i = p / 14, j = p % 14;
    int c = kk >> 8, r = kk & 255;
    int pr = r >> 4, pw = r & 15;
    float v = img[(((size_t)b*3 + c)*224 + i*16 + pr)*224 + j*16 + pw];
    unsigned short hi = f2bf(v);
    ph[idx] = hi;
    pl[idx] = f2bf(v - bfhi(hi));
}

// ---------------- class token + pos row0 ----------------
__global__ __launch_bounds__(256) void class_pos_kernel(const float* __restrict__ ct,
                                                        const float* __restrict__ pos,
                                                        float* __restrict__ x)
{
    int idx = blockIdx.x * 256 + threadIdx.x;
    if (idx >= NIMG * DIM) return;
    int b = idx / DIM, d = idx % DIM;
    x[(size_t)b * PTOK * DIM + d] = ct[d] + pos[d];
}

// ---------------- weight conversion: W[K][N] fp32 -> blocked hi/lo bf16 ----------------
// Blocked: [N/128][K/32][128][32] row-major (n_in, k_in), 4096 elems / 8KB per block.
__device__ __forceinline__ void conv_body(const float* __restrict__ W,
    unsigned short* __restrict__ Bh, unsigned short* __restrict__ Bl, int K, int N)
{
    int idx = blockIdx.x * 256 + threadIdx.x;
    if (idx >= N * (K >> 5)) return;
    int kb = idx / N;
    int n  = idx - kb * N;
    size_t off = (((size_t)(n >> 7) * (K >> 5) + kb) * 128 + (n & 127)) * 32;
    #pragma unroll
    for (int u = 0; u < 4; ++u) {
        u16x8 h, l;
        #pragma unroll
        for (int j = 0; j < 8; ++j) {
            float x = W[(size_t)(kb * 32 + u * 8 + j) * N + n];
            unsigned short hh = f2bf(x);
            h[j] = hh;
            l[j] = f2bf(x - bfhi(hh));
        }
        *(u16x8*)&Bh[off + u * 8] = h;
        *(u16x8*)&Bl[off + u * 8] = l;
    }
}

__global__ __launch_bounds__(256) void convert_one(const float* __restrict__ W,
    unsigned short* __restrict__ Bh, unsigned short* __restrict__ Bl, int K, int N)
{
    conv_body(W, Bh, Bl, K, N);
}

__global__ __launch_bounds__(256) void convert_layer(
    const float* __restrict__ qw, const float* __restrict__ mw,
    const float* __restrict__ w1, const float* __restrict__ w2,
    unsigned short* qh, unsigned short* ql, unsigned short* mh, unsigned short* ml,
    unsigned short* h1, unsigned short* l1, unsigned short* h2, unsigned short* l2)
{
    switch (blockIdx.y) {
        case 0: conv_body(qw, qh, ql, DIM, 3*NH*VD); break;
        case 1: conv_body(mw, mh, ml, DIM, DIM);     break;
        case 2: conv_body(w1, h1, l1, DIM, MLPD);    break;
        case 3: conv_body(w2, h2, l2, MLPD, DIM);    break;
    }
}

// ---------------- shared epilogue ----------------
template<int MODE>
__device__ __forceinline__ void epi_store(
    int r, int c, float val, float* __restrict__ C, int M, int N,
    const float* __restrict__ bias, const float* __restrict__ res,
    const float* __restrict__ pos,
    unsigned int* __restrict__ qo, unsigned int* __restrict__ ko, unsigned int* __restrict__ vo,
    unsigned short* __restrict__ oph, unsigned short* __restrict__ opl)
{
    if (MODE == 1) {
        int b = r / NP2, p = r - b * NP2;
        C[((size_t)b * PTOK + 1 + p) * DIM + c] = val + pos[(size_t)(p + 1) * DIM + c];
    } else if (MODE == 2) {
        int b = r / PTOK, p = r - b * PTOK;
        int t = c % 3, hv = c / 3;
        int hd = hv >> 6, vv = hv & 63;
        size_t bh = (size_t)b * NH + hd;
        float sv = (t == 0) ? val * 0.125f : val;
        unsigned short hi = f2bf(sv);
        unsigned short lo = f2bf(sv - bfhi(hi));
        unsigned int w32 = (unsigned int)hi | ((unsigned int)lo << 16);
        if (t == 2) vo[(bh * 64 + vv) * PSTR + p] = w32;
        else if (t == 0) qo[(bh * PSTR + p) * 64 + vv] = w32;
        else ko[(bh * PSTR + p) * 64 + vv] = w32;
    } else if (MODE == 3) {
        float tmp = val + bias[c];
        float gel = 0.5f * tmp * (1.0f + erff(tmp * 0.70710678118654752f));
        unsigned short hi = f2bf(gel);
        oph[(size_t)r * N + c] = hi;
        opl[(size_t)r * N + c] = f2bf(gel - bfhi(hi));
    } else if (MODE == 4) {
        C[(size_t)r * N + c] = res[(size_t)r * N + c] + val;
    } else if (MODE == 5) {
        C[(size_t)r * N + c] = res[(size_t)r * N + c] + val + bias[c];
    }
}

// ---------------- mgemm: 128x128 tile, single 32KB buffer, 4 blocks/CU (r9, converged) ----------------
// Drain-then-compute; latency hidden by TLP (16 waves/CU, m114 implicit overlap).
// Bijective XCD chunking keeps FETCH at the per-XCD floor (r6: 200->93MB).
// Runs MFMAs at ~642 TF = 73% of the m97-structure ceiling; the remaining gap is the
// hi/lo split's 2x staging bytes. All structural alternatives measured worse:
// 2-phase dbuf (r7), 256^2 1-block/CU (r8), (512,6)/(512,4) spill (r5/r10),
// supertile walk (r11), A-from-L2 (r12), 256x128 2-block/CU (r13).
// Register budget: 64 VGPR + 64 AGPR(acc) = 128 = (256,4) cap. Do NOT add live regs.
template<int MODE>
__global__ __launch_bounds__(256, 4) void mgemm(
    const unsigned short* __restrict__ Ah, const unsigned short* __restrict__ Al,
    const unsigned short* __restrict__ Bh, const unsigned short* __restrict__ Bl,
    float* __restrict__ C, int M, int N, int K, int gm, int gn,
    const float* __restrict__ bias, const float* __restrict__ res,
    const float* __restrict__ pos,
    unsigned int* __restrict__ qo, unsigned int* __restrict__ ko, unsigned int* __restrict__ vo,
    unsigned short* __restrict__ oph, unsigned short* __restrict__ opl)
{
    __shared__ unsigned short SAh[4096];
    __shared__ unsigned short SAl[4096];
    __shared__ unsigned short SBh[4096];
    __shared__ unsigned short SBl[4096];

    const int tid = threadIdx.x;
    const int nwg = gm * gn;
    const int q = nwg >> 3, r = nwg & 7;
    const int xcd = blockIdx.x & 7, li = blockIdx.x >> 3;
    const int seq = xcd * q + (xcd < r ? xcd : r) + li;
    const int mt = seq / gn, nt = seq - mt * gn;
    const int m0 = mt * 128, n0 = nt * 128;

    const int wave = tid >> 6, lane = tid & 63;
    const int wm = (wave >> 1) * 64, wn = (wave & 1) * 64;
    const int lr = lane & 15, lg = lane >> 4;

    const int r0 = tid >> 2, sl = tid & 3;
    const int s0 = sl ^ ((r0 >> 1) & 3);
    const size_t aoff0 = (size_t)(m0 + r0) * K + s0 * 8;
    const size_t aoff1 = (size_t)(m0 + r0 + 64) * K + s0 * 8;
    const size_t boff0 = (size_t)(n0 >> 7) * (K >> 5) * 4096 + (size_t)r0 * 32 + s0 * 8;

    int aro[4], bro[4];
    #pragma unroll
    for (int i = 0; i < 4; ++i) {
        int rowA = wm + i * 16 + lr;
        aro[i] = rowA * 32 + ((lg ^ ((rowA >> 1) & 3)) * 8);
        int rowB = wn + i * 16 + lr;
        bro[i] = rowB * 32 + ((lg ^ ((rowB >> 1) & 3)) * 8);
    }

    f32x4 acc[4][4];
    #pragma unroll
    for (int i = 0; i < 4; ++i)
        #pragma unroll
        for (int j = 0; j < 4; ++j)
            #pragma unroll
            for (int e = 0; e < 4; ++e) acc[i][j][e] = 0.f;

    const int kSteps = K >> 5;
    #pragma unroll 1
    for (int ks = 0; ks < kSteps; ++ks) {
        __syncthreads();                 // prev frag reads done
        const size_t ak = (size_t)ks * 32;
        const size_t bk = (size_t)ks * 4096;
        glds16(Ah + aoff0 + ak, SAh + tid * 8);
        glds16(Ah + aoff1 + ak, SAh + 2048 + tid * 8);
        glds16(Al + aoff0 + ak, SAl + tid * 8);
        glds16(Al + aoff1 + ak, SAl + 2048 + tid * 8);
        glds16(Bh + boff0 + bk, SBh + tid * 8);
        glds16(Bh + boff0 + bk + 2048, SBh + 2048 + tid * 8);
        glds16(Bl + boff0 + bk, SBl + tid * 8);
        glds16(Bl + boff0 + bk + 2048, SBl + 2048 + tid * 8);
        __syncthreads();                 // drains vmcnt before barrier

        bf16x8 bfh[4], bfl[4];
        #pragma unroll
        for (int ni = 0; ni < 4; ++ni) {
            bfh[ni] = *(const bf16x8*)&SBh[bro[ni]];
            bfl[ni] = *(const bf16x8*)&SBl[bro[ni]];
        }
        #pragma unroll
        for (int mi = 0; mi < 4; ++mi) {
            bf16x8 afh = *(const bf16x8*)&SAh[aro[mi]];
            bf16x8 afl = *(const bf16x8*)&SAl[aro[mi]];
            #pragma unroll
            for (int ni = 0; ni < 4; ++ni) {
                acc[mi][ni] = __builtin_amdgcn_mfma_f32_16x16x32_bf16(afh, bfh[ni], acc[mi][ni], 0, 0, 0);
                acc[mi][ni] = __builtin_amdgcn_mfma_f32_16x16x32_bf16(afh, bfl[ni], acc[mi][ni], 0, 0, 0);
                acc[mi][ni] = __builtin_amdgcn_mfma_f32_16x16x32_bf16(afl, bfh[ni], acc[mi][ni], 0, 0, 0);
            }
        }
    }

    #pragma unroll
    for (int mi = 0; mi < 4; ++mi) {
        #pragma unroll
        for (int ni = 0; ni < 4; ++ni) {
            f32x4 v = acc[mi][ni];
            int c = n0 + wn + ni * 16 + lr;
            #pragma unroll
            for (int rr = 0; rr < 4; ++rr) {
                int rr2 = m0 + wm + mi * 16 + lg * 4 + rr;
                if (rr2 >= M) continue;
                epi_store<MODE>(rr2, c, v[rr], C, M, N, bias, res, pos, qo, ko, vo, oph, opl);
            }
        }
    }
}

// ---------------- LayerNorm -> hi/lo bf16 planes ----------------
__global__ __launch_bounds__(256) void ln_kernel(const float* __restrict__ x,
                                                 const float* __restrict__ w,
                                                 const float* __restrict__ b,
                                                 unsigned short* __restrict__ oh,
                                                 unsigned short* __restrict__ ol, int rows)
{
    int wave = threadIdx.x >> 6, lane = threadIdx.x & 63;
    int row = blockIdx.x * 4 + wave;
    if (row >= rows) return;
    const float* xr = x + (size_t)row * DIM;
    float vals[12];
    float sum = 0.f;
    #pragma unroll
    for (int u = 0; u < 12; ++u) { vals[u] = xr[u * 64 + lane]; sum += vals[u]; }
    #pragma unroll
    for (int off = 32; off; off >>= 1) sum += __shfl_xor(sum, off);
    float mean = sum * (1.f / DIM);
    float vs = 0.f;
    #pragma unroll
    for (int u = 0; u < 12; ++u) { float d = vals[u] - mean; vs += d * d; }
    #pragma unroll
    for (int off = 32; off; off >>= 1) vs += __shfl_xor(vs, off);
    float rstd = rsqrtf(vs * (1.f / DIM) + 1e-5f);
    #pragma unroll
    for (int u = 0; u < 12; ++u) {
        int d = u * 64 + lane;
        float v = (vals[u] - mean) * rstd * w[d] + b[d];
        unsigned short hi = f2bf(v);
        oh[(size_t)row * DIM + d] = hi;
        ol[(size_t)row * DIM + d] = f2bf(v - bfhi(hi));
    }
}

// ---------------- MFMA attention (epilogue -> hi/lo planes) ----------------
__global__ __launch_bounds__(256) void attn_mfma(
    const unsigned int* __restrict__ qp, const unsigned int* __restrict__ kp,
    const unsigned int* __restrict__ vtp,
    unsigned short* __restrict__ oh, unsigned short* __restrict__ ol)
{
    __shared__ unsigned short KVh[64 * 72];
    __shared__ unsigned short KVl[64 * 72];
    __shared__ unsigned short Ph[64 * 72];
    __shared__ unsigned short Pl[64 * 72];

    const int tid = threadIdx.x;
    const int w = tid >> 6, lane = tid & 63;
    const int l = lane & 15, g = lane >> 4;
    const int bh = blockIdx.y, q0 = blockIdx.x * 64;
    const int b = bh / NH, hd = bh - b * NH;

    int qrow = q0 + 16 * w + l;
    if (qrow >= PTOK) qrow = 0;
    const unsigned int* qbase = qp + ((size_t)bh * PSTR + qrow) * 64;
    bf16x8 qAh[2], qAl[2];
    #pragma unroll
    for (int ks = 0; ks < 2; ++ks) {
        const unsigned int* p = qbase + 32 * ks + 8 * g;
        uint4 a = *(const uint4*)p;
        uint4 c = *(const uint4*)(p + 4);
        bf16x8 h8, l8;
        h8[0]=(short)a.x; h8[1]=(short)a.y; h8[2]=(short)a.z; h8[3]=(short)a.w;
        h8[4]=(short)c.x; h8[5]=(short)c.y; h8[6]=(short)c.z; h8[7]=(short)c.w;
        l8[0]=(short)(a.x>>16); l8[1]=(short)(a.y>>16); l8[2]=(short)(a.z>>16); l8[3]=(short)(a.w>>16);
        l8[4]=(short)(c.x>>16); l8[5]=(short)(c.y>>16); l8[6]=(short)(c.z>>16); l8[7]=(short)(c.w>>16);
        qAh[ks] = h8; qAl[ks] = l8;
    }

    f32x4 s[13];
    #pragma unroll
    for (int t = 0; t < 13; ++t)
        #pragma unroll
        for (int e = 0; e < 4; ++e) s[t][e] = 0.f;

    for (int c = 0; c < 4; ++c) {
        __syncthreads();
        const int rows = (c < 3) ? 64 : 16;
        for (int u = tid; u < rows * 16; u += 256) {
            int r = u >> 4, cc = u & 15;
            int j = c * 64 + r;
            uint4 wv = make_uint4(0, 0, 0, 0);
            if (j < PTOK) wv = *(const uint4*)(kp + ((size_t)bh * PSTR + j) * 64 + cc * 4);
            u16x4 h4, l4;
            h4[0]=(unsigned short)wv.x; h4[1]=(unsigned short)wv.y;
            h4[2]=(unsigned short)wv.z; h4[3]=(unsigned short)wv.w;
            l4[0]=(unsigned short)(wv.x>>16); l4[1]=(unsigned short)(wv.y>>16);
            l4[2]=(unsigned short)(wv.z>>16); l4[3]=(unsigned short)(wv.w>>16);
            *(u16x4*)&KVh[r * 72 + cc * 4] = h4;
            *(u16x4*)&KVl[r * 72 + cc * 4] = l4;
        }
        __syncthreads();
        const int tc = (c < 3) ? 4 : 1;
        for (int t = 0; t < tc; ++t) {
            int ti = c * 4 + t;
            #pragma unroll
            for (int ks = 0; ks < 2; ++ks) {
                bf16x8 kh = *(const bf16x8*)&KVh[(16 * t + l) * 72 + 32 * ks + 8 * g];
                bf16x8 kl = *(const bf16x8*)&KVl[(16 * t + l) * 72 + 32 * ks + 8 * g];
                s[ti] = __builtin_amdgcn_mfma_f32_16x16x32_bf16(qAh[ks], kh, s[ti], 0, 0, 0);
                s[ti] = __builtin_amdgcn_mfma_f32_16x16x32_bf16(qAh[ks], kl, s[ti], 0, 0, 0);
                s[ti] = __builtin_amdgcn_mfma_f32_16x16x32_bf16(qAl[ks], kh, s[ti], 0, 0, 0);
            }
        }
    }

    if (l >= 5) {
        #pragma unroll
        for (int e = 0; e < 4; ++e) s[12][e] = -1e30f;
    }

    float mx[4], rs[4];
    #pragma unroll
    for (int e = 0; e < 4; ++e) {
        float m = s[0][e];
        #pragma unroll
        for (int t = 1; t < 13; ++t) m = fmaxf(m, s[t][e]);
        #pragma unroll
        for (int off = 1; off < 16; off <<= 1) m = fmaxf(m, __shfl_xor(m, off));
        mx[e] = m;
    }
    #pragma unroll
    for (int e = 0; e < 4; ++e) {
        float sum = 0.f;
        #pragma unroll
        for (int t = 0; t < 13; ++t) {
            float p = __expf(s[t][e] - mx[e]);
            s[t][e] = p;
            sum += p;
        }
        #pragma unroll
        for (int off = 1; off < 16; off <<= 1) sum += __shfl_xor(sum, off);
        rs[e] = 1.f / sum;
    }

    f32x4 o[4];
    #pragma unroll
    for (int t = 0; t < 4; ++t)
        #pragma unroll
        for (int e = 0; e < 4; ++e) o[t][e] = 0.f;

    for (int c = 0; c < 4; ++c) {
        __syncthreads();
        const int cols = (c < 3) ? 64 : 32;
        const int cpr = cols >> 2;
        for (int u = tid; u < 64 * cpr; u += 256) {
            int r = u / cpr, cc = u % cpr;
            int jbase = c * 64 + cc * 4;
            uint4 wv;
            if (c < 3) {
                wv = *(const uint4*)(vtp + ((size_t)bh * 64 + r) * PSTR + jbase);
            } else {
                unsigned int t0 = (jbase + 0 < PTOK) ? vtp[((size_t)bh * 64 + r) * PSTR + jbase + 0] : 0u;
                unsigned int t1 = (jbase + 1 < PTOK) ? vtp[((size_t)bh * 64 + r) * PSTR + jbase + 1] : 0u;
                unsigned int t2 = (jbase + 2 < PTOK) ? vtp[((size_t)bh * 64 + r) * PSTR + jbase + 2] : 0u;
                unsigned int t3 = (jbase + 3 < PTOK) ? vtp[((size_t)bh * 64 + r) * PSTR + jbase + 3] : 0u;
                wv = make_uint4(t0, t1, t2, t3);
            }
            u16x4 h4, l4;
            h4[0]=(unsigned short)wv.x; h4[1]=(unsigned short)wv.y;
            h4[2]=(unsigned short)wv.z; h4[3]=(unsigned short)wv.w;
            l4[0]=(unsigned short)(wv.x>>16); l4[1]=(unsigned short)(wv.y>>16);
            l4[2]=(unsigned short)(wv.z>>16); l4[3]=(unsigned short)(wv.w>>16);
            *(u16x4*)&KVh[r * 72 + cc * 4] = h4;
            *(u16x4*)&KVl[r * 72 + cc * 4] = l4;
        }
        const int tc = (c < 3) ? 4 : 1;
        for (int t = 0; t < tc; ++t) {
            int ti = c * 4 + t;
            #pragma unroll
            for (int e = 0; e < 4; ++e) {
                int row = 16 * w + 4 * g + e, col = 16 * t + l;
                float pv = s[ti][e];
                unsigned short hi = f2bf(pv);
                Ph[row * 72 + col] = hi;
                Pl[row * 72 + col] = f2bf(pv - bfhi(hi));
            }
        }
        __syncthreads();
        const int ksn = (c < 3) ? 2 : 1;
        for (int ks = 0; ks < ksn; ++ks) {
            bf16x8 pa_h = *(const bf16x8*)&Ph[(16 * w + l) * 72 + 32 * ks + 8 * g];
            bf16x8 pa_l = *(const bf16x8*)&Pl[(16 * w + l) * 72 + 32 * ks + 8 * g];
            #pragma unroll
            for (int tv = 0; tv < 4; ++tv) {
                bf16x8 vh = *(const bf16x8*)&KVh[(16 * tv + l) * 72 + 32 * ks + 8 * g];
                bf16x8 vl = *(const bf16x8*)&KVl[(16 * tv + l) * 72 + 32 * ks + 8 * g];
                o[tv] = __builtin_amdgcn_mfma_f32_16x16x32_bf16(pa_h, vh, o[tv], 0, 0, 0);
                o[tv] = __builtin_amdgcn_mfma_f32_16x16x32_bf16(pa_h, vl, o[tv], 0, 0, 0);
                o[tv] = __builtin_amdgcn_mfma_f32_16x16x32_bf16(pa_l, vh, o[tv], 0, 0, 0);
            }
        }
    }

    #pragma unroll
    for (int tv = 0; tv < 4; ++tv) {
        #pragma unroll
        for (int e = 0; e < 4; ++e) {
            int q = q0 + 16 * w + 4 * g + e;
            if (q < PTOK) {
                float v = o[tv][e] * rs[e];
                size_t idx = ((size_t)(b * PTOK + q)) * DIM + hd * 64 + 16 * tv + l;
                unsigned short hi = f2bf(v);
                oh[idx] = hi;
                ol[idx] = f2bf(v - bfhi(hi));
            }
        }
    }
}

// ---------------- head: logits + softmax ----------------
__global__ __launch_bounds__(256) void head_kernel(const float* __restrict__ x,
                                                   const float* __restrict__ W,
                                                   const float* __restrict__ bias,
                                                   float* __restrict__ out)
{
    __shared__ __align__(16) float xl[DIM];
    __shared__ float red[4];
    int b = blockIdx.x;
    const float* xr = x + (size_t)b * PTOK * DIM;
    for (int idx = threadIdx.x; idx < DIM; idx += 256) xl[idx] = xr[idx];
    __syncthreads();

    float logit[4];
    #pragma unroll
    for (int u = 0; u < 4; ++u) {
        int c = threadIdx.x + u * 256;
        float acc = (c < 1000) ? bias[c] : -INFINITY;
        if (c < 1000) {
            for (int k = 0; k < DIM; k += 4) {
                float4 xv = *(const float4*)&xl[k];
                acc += xv.x * W[(size_t)k * 1000 + c]
                     + xv.y * W[(size_t)(k + 1) * 1000 + c]
                     + xv.z * W[(size_t)(k + 2) * 1000 + c]
                     + xv.w * W[(size_t)(k + 3) * 1000 + c];
            }
        }
        logit[u] = acc;
    }
    int lane = threadIdx.x & 63, wv = threadIdx.x >> 6;
    float m = fmaxf(fmaxf(logit[0], logit[1]), fmaxf(logit[2], logit[3]));
    #pragma unroll
    for (int off = 32; off; off >>= 1) m = fmaxf(m, __shfl_xor(m, off));
    if (lane == 0) red[wv] = m;
    __syncthreads();
    m = fmaxf(fmaxf(red[0], red[1]), fmaxf(red[2], red[3]));

    float p[4]; float sum = 0.f;
    #pragma unroll
    for (int u = 0; u < 4; ++u) {
        int c = threadIdx.x + u * 256;
        p[u] = (c < 1000) ? expf(logit[u] - m) : 0.f;
        sum += p[u];
    }
    #pragma unroll
    for (int off = 32; off; off >>= 1) sum += __shfl_xor(sum, off);
    __syncthreads();
    if (lane == 0) red[wv] = sum;
    __syncthreads();
    float inv = 1.f / (red[0] + red[1] + red[2] + red[3]);
    #pragma unroll
    for (int u = 0; u < 4; ++u) {
        int c = threadIdx.x + u * 256;
        if (c < 1000) out[(size_t)b * 1000 + c] = p[u] * inv;
    }
}

// ---------------- launcher ----------------
extern "C" void kernel_launch(void* const* d_in, const int* in_sizes, int n_in,
                              void* d_out, int out_size, void* d_ws, size_t ws_size,
                              hipStream_t stream)
{
    const float* images  = (const float*)d_in[0];
    const float* W_map   = (const float*)d_in[1];
    const float* ct      = (const float*)d_in[2];
    const float* pos     = (const float*)d_in[3];
    const float* ln1_w   = (const float*)d_in[4];
    const float* ln1_b   = (const float*)d_in[5];
    const float* qkv_w   = (const float*)d_in[6];
    const float* merge_w = (const float*)d_in[7];
    const float* ln2_w   = (const float*)d_in[8];
    const float* ln2_b   = (const float*)d_in[9];
    const float* mlp_w1  = (const float*)d_in[10];
    const float* mlp_b1  = (const float*)d_in[11];
    const float* mlp_w2  = (const float*)d_in[12];
    const float* mlp_b2  = (const float*)d_in[13];
    const float* head_w  = (const float*)d_in[14];
    const float* head_b  = (const float*)d_in[15];
    float* out = (float*)d_out;

    float* ws = (float*)d_ws;
    const size_t XE   = (size_t)ROWS * DIM;
    const size_t PLND = (size_t)MPAD * DIM;    // activation plane (DIM wide)
    const size_t GPL  = (size_t)MPAD * MLPD;   // gelu plane (MLPD wide)

    float* x = ws;
    unsigned short* hh = (unsigned short*)(x + XE);
    unsigned short* hl = hh + PLND;
    unsigned short* oh = hl + PLND;
    unsigned short* ol = oh + PLND;
    unsigned short* gh = ol + PLND;
    unsigned short* gl = gh + GPL;

    // aliases on g region (lifetimes disjoint)
    const size_t PL = (size_t)BHN * PSTR * 64;         // q/k/v packed planes
    unsigned int* qpl = (unsigned int*)gh;             // live qkv->attn
    unsigned int* kpl = qpl + PL;
    unsigned int* vtp = kpl + PL;
    unsigned short* pph = gh;                          // patches live pre-loop
    unsigned short* ppl = pph + PLND;                  // MPAD spacing (over-read safe)

    // weight hi/lo planes after gl
    unsigned short* wb = gl + GPL;
    const size_t qkvE = (size_t)DIM * 2304;
    const size_t mgE  = (size_t)DIM * DIM;
    const size_t m1E  = (size_t)DIM * MLPD;
    const size_t m2E  = (size_t)MLPD * DIM;
    unsigned short* qh  = wb;
    unsigned short* ql  = qh  + qkvE;
    unsigned short* mh  = ql  + qkvE;
    unsigned short* ml  = mh  + mgE;
    unsigned short* h1  = ml  + mgE;
    unsigned short* l1  = h1  + m1E;
    unsigned short* h2  = l1  + m1E;
    unsigned short* l2  = h2  + m2E;
    unsigned short* wmh = l2  + m2E;
    unsigned short* wml = wmh + mgE;

    patchify_kernel<<<(PROWS * DIM + 255) / 256, 256, 0, stream>>>(images, pph, ppl);
    class_pos_kernel<<<(NIMG * DIM + 255) / 256, 256, 0, stream>>>(ct, pos, x);
    convert_one<<<(DIM * (DIM / 32) + 255) / 256, 256, 0, stream>>>(W_map, wmh, wml, DIM, DIM);

    const int gme = 49;  // embed: 49*128 = 6272 = PROWS
    mgemm<1><<<gme * 6, 256, 0, stream>>>(
        pph, ppl, wmh, wml, x, PROWS, DIM, DIM, gme, 6,
        nullptr, nullptr, pos, nullptr, nullptr, nullptr, nullptr, nullptr);

    const int gm = 50;   // 128-row tiles: 50*128 = 6400 = MPAD
    for (int l = 0; l < 12; ++l) {
        convert_layer<<<dim3(288, 4), 256, 0, stream>>>(
            qkv_w + (size_t)l * qkvE, merge_w + (size_t)l * mgE,
            mlp_w1 + (size_t)l * m1E, mlp_w2 + (size_t)l * m2E,
            qh, ql, mh, ml, h1, l1, h2, l2);
        ln_kernel<<<(ROWS + 3) / 4, 256, 0, stream>>>(x, ln1_w + l * DIM, ln1_b + l * DIM, hh, hl, ROWS);
        mgemm<2><<<gm * 18, 256, 0, stream>>>(
            hh, hl, qh, ql, nullptr, ROWS, 2304, DIM, gm, 18,
            nullptr, nullptr, nullptr, qpl, kpl, vtp, nullptr, nullptr);
        attn_mfma<<<dim3(4, BHN), 256, 0, stream>>>(qpl, kpl, vtp, oh, ol);
        mgemm<4><<<gm * 6, 256, 0, stream>>>(
            oh, ol, mh, ml, x, ROWS, DIM, DIM, gm, 6,
            nullptr, x, nullptr, nullptr, nullptr, nullptr, nullptr, nullptr);
        ln_kernel<<<(ROWS + 3) / 4, 256, 0, stream>>>(x, ln2_w + l * DIM, ln2_b + l * DIM, hh, hl, ROWS);
        mgemm<3><<<gm * 24, 256, 0, stream>>>(
            hh, hl, h1, l1, nullptr, ROWS, MLPD, DIM, gm, 24,
            mlp_b1 + (size_t)l * MLPD, nullptr, nullptr, nullptr, nullptr, nullptr, gh, gl);
        mgemm<5><<<gm * 6, 256, 0, stream>>>(
            gh, gl, h2, l2, x, ROWS, DIM, MLPD, gm, 6,
            mlp_b2 + (size_t)l * DIM, x, nullptr, nullptr, nullptr, nullptr, nullptr, nullptr);
    }
    head_kernel<<<NIMG, 256, 0, stream>>>(x, head_w, head_b, out);
}